// Round 9
// baseline (3618.625 us; speedup 1.0000x reference)
//
#include <hip/hip_runtime.h>
#include <math.h>

// SchNet forward, MI355X. Round 9: A-operand taken out of LDS.
// r8 pipe accounting: LDS port ~27us + ~12us conflicts dominated the 62.6us
// node GEMM (MFMA only 9.2us). A-fragments are globally coalescible
// (16 rows x 128B per wave-chunk) and the packed hi|lo int format unpacks
// with v_perm in-register -> A: global->reg->perm->MFMA (no barrier dep);
// B: LDS double-buffered (one barrier/chunk, was two).
// Retained: segment pool + batched tab GEMMs (r7/8), packed hi/lo + HP=608
// (r5), XCD swizzle (r4), CSR gather (r2), filter table + lerp (r1).

#define N_ATOMS 10000
#define E_EDGES 64000
#define B_MOLS  128
#define H_DIM   600
#define HP      608            // padded leading dim (608*4B = 38 sectors)
#define G_DIM   50
#define L_LAYERS 6
#define M_TAB   1024
#define DMAX    8.67f
#define LOG2C   0.69314718056f

#define TM 64
#define TN 64
#define TK 32
#define SA 40          // LDS row stride in shorts (80B rows, 2-way banks = free)

typedef __attribute__((ext_vector_type(8))) short bf16x8;
typedef __attribute__((ext_vector_type(4))) float f32x4;

__device__ __forceinline__ float sspf(float x) {
    return fmaxf(x, 0.0f) + log1pf(expf(-fabsf(x))) - LOG2C;
}
__device__ __forceinline__ short f2bf(float x) {
    unsigned u = __float_as_uint(x);
    unsigned r = (u + 0x7FFF + ((u >> 16) & 1)) >> 16;   // RNE
    return (short)r;
}
__device__ __forceinline__ float bf2f(short h) {
    return __uint_as_float(((unsigned)(unsigned short)h) << 16);
}
__device__ __forceinline__ int packsplit(float x) {
    short hi = f2bf(x);
    short lo = f2bf(x - bf2f(hi));
    return ((int)hi << 16) | ((int)lo & 0xffff);
}
__device__ __forceinline__ float unpackf(int p) {
    float fh = __uint_as_float((unsigned)p & 0xffff0000u);
    float fl = __uint_as_float(((unsigned)p) << 16);
    return fh + fl;
}

// v_perm extraction: packed p = hi<<16|lo.
// permhi(p0,p1) = {hi(p0) in low short, hi(p1) in high short}
__device__ __forceinline__ int permhi(int p0, int p1) {
    return (int)__builtin_amdgcn_perm((unsigned)p1, (unsigned)p0, 0x07060302u);
}
__device__ __forceinline__ int permlo(int p0, int p1) {
    return (int)__builtin_amdgcn_perm((unsigned)p1, (unsigned)p0, 0x05040100u);
}
__device__ __forceinline__ bf16x8 mk8(int a, int b, int c, int d) {
    union { int i[4]; bf16x8 v; } u;
    u.i[0] = a; u.i[1] = b; u.i[2] = c; u.i[3] = d;
    return u.v;
}

// ---------------------------------------------------------------- MFMA GEMM
// outP = packsplit(op(A @ B + bias [+ unpack(outP)])). A: packed int [Ma][lda]
// (zero-padded cols), read DIRECTLY from global per wave (coalesced 16rowsx128B).
// B: TRANSPOSED pre-split bf16 hi/lo [Nc][ldb], staged via double-buffered LDS.
// K % 32 == 0. Output ld = HP, pad cols 0. 1D grid, XCD swizzle.
template<bool BIAS, bool ACT, bool ACCUM>
__global__ __launch_bounds__(256, 6)
void gemm_mfma(const int* __restrict__ A, int lda,
               const short* __restrict__ Bh, const short* __restrict__ Bl, int ldb,
               const float* __restrict__ bias,
               int* __restrict__ outP,
               int Ma, int K, int Nc)
{
    const int NT = (Nc + TN - 1) / TN;
    const int f = blockIdx.x;
    const int xcd = f & 7, s = f >> 3;
    const int n0 = (s % NT) * TN;
    const int m0 = (xcd + 8 * (s / NT)) * TM;
    if (m0 >= Ma) return;

    __shared__ __align__(16) short Bs[2][2][TN * SA];   // [buf][hi/lo][n][k]

    const int tid = threadIdx.x;
    const int lane = tid & 63, wid = tid >> 6;
    const int wm = (wid >> 1) * 32, wn = (wid & 1) * 32;
    const int l15 = lane & 15, quad = lane >> 4;
    const int srow = tid >> 2;          // B staging: 0..63
    const int skk  = (tid & 3) << 3;    // 0,8,16,24 shorts

    // A-direct addressing: per mi, row and validity are loop-invariant
    int arow[2]; bool aval[2];
    #pragma unroll
    for (int mi = 0; mi < 2; ++mi) {
        arow[mi] = m0 + wm + mi * 16 + l15;
        aval[mi] = arow[mi] < Ma;
    }

    f32x4 acc[2][2];
    #pragma unroll
    for (int i = 0; i < 2; ++i)
        #pragma unroll
        for (int j = 0; j < 2; ++j)
            acc[i][j] = (f32x4){0.f, 0.f, 0.f, 0.f};

    int4 pa[2][2];                       // packed A chunk: [mi][half]
    short4 rbh0, rbh1, rbl0, rbl1;       // B staging regs

    // ---- prologue: chunk 0
    #pragma unroll
    for (int mi = 0; mi < 2; ++mi) {
        if (aval[mi]) {
            const int* ap = A + (size_t)arow[mi] * lda + quad * 8;
            pa[mi][0] = *(const int4*)ap;
            pa[mi][1] = *(const int4*)(ap + 4);
        } else {
            pa[mi][0] = make_int4(0, 0, 0, 0);
            pa[mi][1] = make_int4(0, 0, 0, 0);
        }
    }
    {
        int gn = n0 + srow;
        if (gn < Nc) {
            const short* bp = Bh + (size_t)gn * ldb + skk;
            const short* lp = Bl + (size_t)gn * ldb + skk;
            rbh0 = *(const short4*)bp; rbh1 = *(const short4*)(bp + 4);
            rbl0 = *(const short4*)lp; rbl1 = *(const short4*)(lp + 4);
        } else { rbh0 = {0,0,0,0}; rbh1 = {0,0,0,0};
                 rbl0 = {0,0,0,0}; rbl1 = {0,0,0,0}; }
        *(short4*)&Bs[0][0][srow * SA + skk]     = rbh0;
        *(short4*)&Bs[0][0][srow * SA + skk + 4] = rbh1;
        *(short4*)&Bs[0][1][srow * SA + skk]     = rbl0;
        *(short4*)&Bs[0][1][srow * SA + skk + 4] = rbl1;
    }
    __syncthreads();

    int cur = 0;
    for (int k0 = 0; k0 < K; k0 += TK, cur ^= 1) {
        // B fragments from LDS (valid via last barrier)
        bf16x8 b_h[2], b_l[2];
        #pragma unroll
        for (int ni = 0; ni < 2; ++ni) {
            int col = wn + ni * 16 + l15;
            b_h[ni] = *(const bf16x8*)&Bs[cur][0][col * SA + quad * 8];
            b_l[ni] = *(const bf16x8*)&Bs[cur][1][col * SA + quad * 8];
        }
        // A fragments: perm-extract hi/lo planes from packed regs
        bf16x8 a_h[2], a_l[2];
        #pragma unroll
        for (int mi = 0; mi < 2; ++mi) {
            int4 p0 = pa[mi][0], p1 = pa[mi][1];
            a_h[mi] = mk8(permhi(p0.x, p0.y), permhi(p0.z, p0.w),
                          permhi(p1.x, p1.y), permhi(p1.z, p1.w));
            a_l[mi] = mk8(permlo(p0.x, p0.y), permlo(p0.z, p0.w),
                          permlo(p1.x, p1.y), permlo(p1.z, p1.w));
        }

        // issue next-chunk loads (overlap the MFMA block below)
        int kn = k0 + TK;
        const bool more = kn < K;
        if (more) {
            #pragma unroll
            for (int mi = 0; mi < 2; ++mi) {
                if (aval[mi]) {
                    const int* ap = A + (size_t)arow[mi] * lda + kn + quad * 8;
                    pa[mi][0] = *(const int4*)ap;
                    pa[mi][1] = *(const int4*)(ap + 4);
                } else {
                    pa[mi][0] = make_int4(0, 0, 0, 0);
                    pa[mi][1] = make_int4(0, 0, 0, 0);
                }
            }
            int gn = n0 + srow;
            if (gn < Nc) {
                const short* bp = Bh + (size_t)gn * ldb + kn + skk;
                const short* lp = Bl + (size_t)gn * ldb + kn + skk;
                rbh0 = *(const short4*)bp; rbh1 = *(const short4*)(bp + 4);
                rbl0 = *(const short4*)lp; rbl1 = *(const short4*)(lp + 4);
            } else { rbh0 = {0,0,0,0}; rbh1 = {0,0,0,0};
                     rbl0 = {0,0,0,0}; rbl1 = {0,0,0,0}; }
        }

        #pragma unroll
        for (int mi = 0; mi < 2; ++mi)
            #pragma unroll
            for (int ni = 0; ni < 2; ++ni) {
                acc[mi][ni] = __builtin_amdgcn_mfma_f32_16x16x32_bf16(
                    a_h[mi], b_h[ni], acc[mi][ni], 0, 0, 0);
                acc[mi][ni] = __builtin_amdgcn_mfma_f32_16x16x32_bf16(
                    a_h[mi], b_l[ni], acc[mi][ni], 0, 0, 0);
                acc[mi][ni] = __builtin_amdgcn_mfma_f32_16x16x32_bf16(
                    a_l[mi], b_h[ni], acc[mi][ni], 0, 0, 0);
            }

        if (more) {
            int nxt = cur ^ 1;
            *(short4*)&Bs[nxt][0][srow * SA + skk]     = rbh0;
            *(short4*)&Bs[nxt][0][srow * SA + skk + 4] = rbh1;
            *(short4*)&Bs[nxt][1][srow * SA + skk]     = rbl0;
            *(short4*)&Bs[nxt][1][srow * SA + skk + 4] = rbl1;
        }
        __syncthreads();
    }

    // epilogue: C/D col = lane&15, row = quad*4 + r; full-sector stores
    #pragma unroll
    for (int mi = 0; mi < 2; ++mi) {
        #pragma unroll
        for (int r = 0; r < 4; ++r) {
            int row = m0 + wm + mi * 16 + quad * 4 + r;
            if (row >= Ma) continue;
            #pragma unroll
            for (int ni = 0; ni < 2; ++ni) {
                int col = n0 + wn + ni * 16 + l15;
                if (col >= HP) continue;
                size_t idx = (size_t)row * HP + col;
                float v = 0.0f;
                if (col < Nc) {
                    v = acc[mi][ni][r];
                    if constexpr (BIAS) v += bias[col];
                    if constexpr (ACT)  v = sspf(v);
                    if constexpr (ACCUM) v += unpackf(outP[idx]);
                }
                outP[idx] = packsplit(v);
            }
        }
    }
}

// Batched slab GEMM over all L layers stacked in M (1024 rows per layer).
// Same A-direct + B-dbuf structure. SHAREDA: A rows are (m % 1024).
template<bool SHAREDA, bool ACT>
__global__ __launch_bounds__(256, 6)
void gemm_tab(const int* __restrict__ A, int lda,
              const short* __restrict__ BhBase, const short* __restrict__ BlBase,
              int ldb, int bstride,
              const float* __restrict__ biasBase,
              int* __restrict__ outP,
              int Ma, int K, int Nc)
{
    const int NT = (Nc + TN - 1) / TN;
    const int f = blockIdx.x;
    const int xcd = f & 7, s = f >> 3;
    const int n0 = (s % NT) * TN;
    const int m0 = (xcd + 8 * (s / NT)) * TM;
    if (m0 >= Ma) return;

    const int layer = m0 >> 10;
    const int arow0 = SHAREDA ? (m0 & 1023) : m0;
    const short* __restrict__ Bh = BhBase + (size_t)layer * bstride;
    const short* __restrict__ Bl = BlBase + (size_t)layer * bstride;
    const float* __restrict__ bias = biasBase + (size_t)layer * H_DIM;

    __shared__ __align__(16) short Bs[2][2][TN * SA];

    const int tid = threadIdx.x;
    const int lane = tid & 63, wid = tid >> 6;
    const int wm = (wid >> 1) * 32, wn = (wid & 1) * 32;
    const int l15 = lane & 15, quad = lane >> 4;
    const int srow = tid >> 2;
    const int skk  = (tid & 3) << 3;

    int arow[2];
    #pragma unroll
    for (int mi = 0; mi < 2; ++mi)
        arow[mi] = arow0 + wm + mi * 16 + l15;   // always in-bounds (exact grids)

    f32x4 acc[2][2];
    #pragma unroll
    for (int i = 0; i < 2; ++i)
        #pragma unroll
        for (int j = 0; j < 2; ++j)
            acc[i][j] = (f32x4){0.f, 0.f, 0.f, 0.f};

    int4 pa[2][2];
    short4 rbh0, rbh1, rbl0, rbl1;

    #pragma unroll
    for (int mi = 0; mi < 2; ++mi) {
        const int* ap = A + (size_t)arow[mi] * lda + quad * 8;
        pa[mi][0] = *(const int4*)ap;
        pa[mi][1] = *(const int4*)(ap + 4);
    }
    {
        int gn = n0 + srow;
        if (gn < Nc) {
            const short* bp = Bh + (size_t)gn * ldb + skk;
            const short* lp = Bl + (size_t)gn * ldb + skk;
            rbh0 = *(const short4*)bp; rbh1 = *(const short4*)(bp + 4);
            rbl0 = *(const short4*)lp; rbl1 = *(const short4*)(lp + 4);
        } else { rbh0 = {0,0,0,0}; rbh1 = {0,0,0,0};
                 rbl0 = {0,0,0,0}; rbl1 = {0,0,0,0}; }
        *(short4*)&Bs[0][0][srow * SA + skk]     = rbh0;
        *(short4*)&Bs[0][0][srow * SA + skk + 4] = rbh1;
        *(short4*)&Bs[0][1][srow * SA + skk]     = rbl0;
        *(short4*)&Bs[0][1][srow * SA + skk + 4] = rbl1;
    }
    __syncthreads();

    int cur = 0;
    for (int k0 = 0; k0 < K; k0 += TK, cur ^= 1) {
        bf16x8 b_h[2], b_l[2];
        #pragma unroll
        for (int ni = 0; ni < 2; ++ni) {
            int col = wn + ni * 16 + l15;
            b_h[ni] = *(const bf16x8*)&Bs[cur][0][col * SA + quad * 8];
            b_l[ni] = *(const bf16x8*)&Bs[cur][1][col * SA + quad * 8];
        }
        bf16x8 a_h[2], a_l[2];
        #pragma unroll
        for (int mi = 0; mi < 2; ++mi) {
            int4 p0 = pa[mi][0], p1 = pa[mi][1];
            a_h[mi] = mk8(permhi(p0.x, p0.y), permhi(p0.z, p0.w),
                          permhi(p1.x, p1.y), permhi(p1.z, p1.w));
            a_l[mi] = mk8(permlo(p0.x, p0.y), permlo(p0.z, p0.w),
                          permlo(p1.x, p1.y), permlo(p1.z, p1.w));
        }

        int kn = k0 + TK;
        const bool more = kn < K;
        if (more) {
            #pragma unroll
            for (int mi = 0; mi < 2; ++mi) {
                const int* ap = A + (size_t)arow[mi] * lda + kn + quad * 8;
                pa[mi][0] = *(const int4*)ap;
                pa[mi][1] = *(const int4*)(ap + 4);
            }
            int gn = n0 + srow;
            if (gn < Nc) {
                const short* bp = Bh + (size_t)gn * ldb + kn + skk;
                const short* lp = Bl + (size_t)gn * ldb + kn + skk;
                rbh0 = *(const short4*)bp; rbh1 = *(const short4*)(bp + 4);
                rbl0 = *(const short4*)lp; rbl1 = *(const short4*)(lp + 4);
            } else { rbh0 = {0,0,0,0}; rbh1 = {0,0,0,0};
                     rbl0 = {0,0,0,0}; rbl1 = {0,0,0,0}; }
        }

        #pragma unroll
        for (int mi = 0; mi < 2; ++mi)
            #pragma unroll
            for (int ni = 0; ni < 2; ++ni) {
                acc[mi][ni] = __builtin_amdgcn_mfma_f32_16x16x32_bf16(
                    a_h[mi], b_h[ni], acc[mi][ni], 0, 0, 0);
                acc[mi][ni] = __builtin_amdgcn_mfma_f32_16x16x32_bf16(
                    a_h[mi], b_l[ni], acc[mi][ni], 0, 0, 0);
                acc[mi][ni] = __builtin_amdgcn_mfma_f32_16x16x32_bf16(
                    a_l[mi], b_h[ni], acc[mi][ni], 0, 0, 0);
            }

        if (more) {
            int nxt = cur ^ 1;
            *(short4*)&Bs[nxt][0][srow * SA + skk]     = rbh0;
            *(short4*)&Bs[nxt][0][srow * SA + skk + 4] = rbh1;
            *(short4*)&Bs[nxt][1][srow * SA + skk]     = rbl0;
            *(short4*)&Bs[nxt][1][srow * SA + skk + 4] = rbl1;
        }
        __syncthreads();
    }

    #pragma unroll
    for (int mi = 0; mi < 2; ++mi) {
        #pragma unroll
        for (int r = 0; r < 4; ++r) {
            int row = m0 + wm + mi * 16 + quad * 4 + r;
            if (row >= Ma) continue;
            #pragma unroll
            for (int ni = 0; ni < 2; ++ni) {
                int col = n0 + wn + ni * 16 + l15;
                if (col >= HP) continue;
                float v = 0.0f;
                if (col < Nc) {
                    v = acc[mi][ni][r] + bias[col];
                    if constexpr (ACT) v = sspf(v);
                }
                outP[(size_t)row * HP + col] = packsplit(v);
            }
        }
    }
}

static inline dim3 mfma_grid(int Ma, int Nc) {
    int MB = (Ma + TM - 1) / TM;
    int NT = (Nc + TN - 1) / TN;
    int Ys = ((MB + 7) / 8) * 8;
    return dim3(Ys * NT);
}

// ---------------------------------------------------------------- fp32 GEMM (final pool matmul only)
#define BM 64
#define BN 64
#define BK 16
template<bool BIAS>
__global__ __launch_bounds__(256)
void gemm_k(const float* __restrict__ A, int lda,
            const float* __restrict__ W,
            const float* __restrict__ bias,
            float* __restrict__ out,
            int Ma, int K, int Nc)
{
    __shared__ __align__(16) float Asd[BK][BM];
    __shared__ __align__(16) float Bsd[BK][BN];
    const int tid = threadIdx.x;
    const int tx = tid & 15, ty = tid >> 4;
    const int m0 = blockIdx.y * BM, n0 = blockIdx.x * BN;
    const int ar = tid >> 2, ac = (tid & 3) << 2;
    const int br = tid >> 4, bc = (tid & 15) << 2;
    float acc[4][4] = {};
    for (int k0 = 0; k0 < K; k0 += BK) {
        {
            int row = m0 + ar, col = k0 + ac;
            float4 v = make_float4(0.f, 0.f, 0.f, 0.f);
            if (row < Ma) {
                const float* ap = A + (size_t)row * lda + col;
                if (col + 3 < K) v = *(const float4*)ap;
                else {
                    if (col + 0 < K) v.x = ap[0];
                    if (col + 1 < K) v.y = ap[1];
                    if (col + 2 < K) v.z = ap[2];
                }
            }
            Asd[ac + 0][ar] = v.x; Asd[ac + 1][ar] = v.y;
            Asd[ac + 2][ar] = v.z; Asd[ac + 3][ar] = v.w;
        }
        {
            int row = k0 + br, col = n0 + bc;
            float4 v = make_float4(0.f, 0.f, 0.f, 0.f);
            if (row < K && col + 3 < Nc)
                v = *(const float4*)(W + (size_t)row * Nc + col);
            *(float4*)&Bsd[br][bc] = v;
        }
        __syncthreads();
        #pragma unroll
        for (int kk = 0; kk < BK; ++kk) {
            float4 a4 = *(const float4*)&Asd[kk][ty << 2];
            float4 b4 = *(const float4*)&Bsd[kk][tx << 2];
            float av[4] = {a4.x, a4.y, a4.z, a4.w};
            float bv[4] = {b4.x, b4.y, b4.z, b4.w};
            #pragma unroll
            for (int i = 0; i < 4; ++i)
                #pragma unroll
                for (int j = 0; j < 4; ++j)
                    acc[i][j] = fmaf(av[i], bv[j], acc[i][j]);
        }
        __syncthreads();
    }
    #pragma unroll
    for (int i = 0; i < 4; ++i) {
        int row = m0 + (ty << 2) + i;
        if (row >= Ma) continue;
        #pragma unroll
        for (int j = 0; j < 4; ++j) {
            int col = n0 + (tx << 2) + j;
            if (col >= Nc) continue;
            float v = acc[i][j];
            if constexpr (BIAS) v += bias[col];
            out[(size_t)row * Nc + col] = v;
        }
    }
}

// ---------------------------------------------------------------- weight prep
__global__ __launch_bounds__(256)
void wts_w1_k(const float* __restrict__ w_all, short* __restrict__ oh,
              short* __restrict__ ol)
{
    __shared__ short th[64][65], tl[64][65];
    const int layer = blockIdx.z;
    const float* w = w_all + (size_t)layer * G_DIM * H_DIM;
    short* ohz = oh + (size_t)layer * H_DIM * 64;
    short* olz = ol + (size_t)layer * H_DIM * 64;
    const int n0 = blockIdx.y * 64;
    const int tid = threadIdx.x;
    #pragma unroll
    for (int p = 0; p < 4; ++p) {
        int k = p * 16 + (tid >> 4);
        int n4 = (tid & 15) << 2;
        float4 v = make_float4(0.f, 0.f, 0.f, 0.f);
        if (k < G_DIM && n0 + n4 + 3 < H_DIM)
            v = *(const float4*)(w + (size_t)k * H_DIM + n0 + n4);
        int px = packsplit(v.x), py = packsplit(v.y);
        int pz = packsplit(v.z), pw = packsplit(v.w);
        th[n4 + 0][k] = (short)(px >> 16); tl[n4 + 0][k] = (short)px;
        th[n4 + 1][k] = (short)(py >> 16); tl[n4 + 1][k] = (short)py;
        th[n4 + 2][k] = (short)(pz >> 16); tl[n4 + 2][k] = (short)pz;
        th[n4 + 3][k] = (short)(pw >> 16); tl[n4 + 3][k] = (short)pw;
    }
    __syncthreads();
    #pragma unroll
    for (int p = 0; p < 4; ++p) {
        int n = p * 16 + (tid >> 4);
        int k4 = (tid & 15) << 2;
        if (n0 + n >= H_DIM) continue;
        short4 sh = { th[n][k4], th[n][k4 + 1], th[n][k4 + 2], th[n][k4 + 3] };
        short4 sl = { tl[n][k4], tl[n][k4 + 1], tl[n][k4 + 2], tl[n][k4 + 3] };
        *(short4*)(ohz + (size_t)(n0 + n) * 64 + k4) = sh;
        *(short4*)(olz + (size_t)(n0 + n) * 64 + k4) = sl;
    }
}

__global__ __launch_bounds__(256)
void wts_big_k(const float* __restrict__ w2, const float* __restrict__ l1,
               const float* __restrict__ l2, const float* __restrict__ iw,
               short* __restrict__ oh2, short* __restrict__ ol2,
               short* __restrict__ oh1, short* __restrict__ ol1,
               short* __restrict__ ohl2, short* __restrict__ oll2,
               short* __restrict__ ohi, short* __restrict__ oli)
{
    __shared__ short th[64][65], tl[64][65];
    const int z = blockIdx.z, type = z / L_LAYERS, layer = z % L_LAYERS;
    const float* w; short* oh; short* ol;
    if (type == 0)      { w = w2; oh = oh2; ol = ol2; }
    else if (type == 1) { w = l1; oh = oh1; ol = ol1; }
    else if (type == 2) { w = l2; oh = ohl2; ol = oll2; }
    else                { w = iw; oh = ohi; ol = oli; }
    w  += (size_t)layer * H_DIM * H_DIM;
    oh += (size_t)layer * H_DIM * HP;
    ol += (size_t)layer * H_DIM * HP;
    const int k0 = blockIdx.x * 64, n0 = blockIdx.y * 64;
    const int tid = threadIdx.x;
    #pragma unroll
    for (int p = 0; p < 4; ++p) {
        int k = p * 16 + (tid >> 4);
        int n4 = (tid & 15) << 2;
        float4 v = make_float4(0.f, 0.f, 0.f, 0.f);
        if (k0 + k < H_DIM && n0 + n4 + 3 < H_DIM)
            v = *(const float4*)(w + (size_t)(k0 + k) * H_DIM + n0 + n4);
        int px = packsplit(v.x), py = packsplit(v.y);
        int pz = packsplit(v.z), pw = packsplit(v.w);
        th[n4 + 0][k] = (short)(px >> 16); tl[n4 + 0][k] = (short)px;
        th[n4 + 1][k] = (short)(py >> 16); tl[n4 + 1][k] = (short)py;
        th[n4 + 2][k] = (short)(pz >> 16); tl[n4 + 2][k] = (short)pz;
        th[n4 + 3][k] = (short)(pw >> 16); tl[n4 + 3][k] = (short)pw;
    }
    __syncthreads();
    #pragma unroll
    for (int p = 0; p < 4; ++p) {
        int n = p * 16 + (tid >> 4);
        int k4 = (tid & 15) << 2;
        if (n0 + n >= H_DIM || k0 + k4 > HP - 4) continue;
        short4 sh = { th[n][k4], th[n][k4 + 1], th[n][k4 + 2], th[n][k4 + 3] };
        short4 sl = { tl[n][k4], tl[n][k4 + 1], tl[n][k4 + 2], tl[n][k4 + 3] };
        *(short4*)(oh + (size_t)(n0 + n) * HP + k0 + k4) = sh;
        *(short4*)(ol + (size_t)(n0 + n) * HP + k0 + k4) = sl;
    }
}

// ---------------------------------------------------------------- helpers
__global__ __launch_bounds__(256)
void init_h_k(const int* __restrict__ z, const float* __restrict__ emb,
              int* __restrict__ hP)
{
    int t = blockIdx.x * 256 + threadIdx.x;
    const int QC = HP / 4;   // 152
    if (t >= N_ATOMS * QC) return;
    int i = t / QC;
    int q = (t - i * QC) << 2;
    size_t idx = (size_t)i * HP + q;
    if (q < H_DIM) {
        float4 v = *(const float4*)(emb + (size_t)z[i] * H_DIM + q);
        *(int4*)(hP + idx) = make_int4(packsplit(v.x), packsplit(v.y),
                                       packsplit(v.z), packsplit(v.w));
    } else {
        *(int4*)(hP + idx) = make_int4(0, 0, 0, 0);
    }
}

// per-edge record: {src*HP, i0*HP, a = C - f*C, b = f*C}
__global__ __launch_bounds__(256)
void edge_geom_k(const float* __restrict__ pos, const int* __restrict__ src,
                 const int* __restrict__ dst, float4* __restrict__ einfo)
{
    int e = blockIdx.x * 256 + threadIdx.x;
    if (e >= E_EDGES) return;
    int s = src[e], d0 = dst[e];
    float dx = pos[s * 3 + 0] - pos[d0 * 3 + 0];
    float dy = pos[s * 3 + 1] - pos[d0 * 3 + 1];
    float dz = pos[s * 3 + 2] - pos[d0 * 3 + 2];
    float dist = sqrtf(dx * dx + dy * dy + dz * dz + 1e-12f);
    float cc = 0.5f * (cosf(dist * 0.31415926535f) + 1.0f);
    float u = dist * ((float)(M_TAB - 1) / DMAX);
    u = fminf(fmaxf(u, 0.0f), (float)(M_TAB - 1) - 0.001f);
    int i0 = (int)u;
    float fc = (u - (float)i0) * cc;
    einfo[e] = make_float4(__int_as_float(s * HP),
                           __int_as_float(i0 * HP),
                           cc - fc, fc);
}

__global__ __launch_bounds__(256)
void rbf_tab_k(int* __restrict__ rtabP)
{
    int t = blockIdx.x * 256 + threadIdx.x;
    if (t >= M_TAB * 64) return;
    int i = t >> 6, g = t & 63;
    float v = 0.0f;
    if (g < G_DIM) {
        float dg  = (float)i * (DMAX / (float)(M_TAB - 1));
        float off = (float)g * (10.0f / 49.0f);
        float x = dg - off;
        const float coeff = -0.5f * (49.0f / 10.0f) * (49.0f / 10.0f);
        v = expf(coeff * x * x);
    }
    rtabP[t] = packsplit(v);
}

// ---------------------------------------------------------------- CSR build
__global__ __launch_bounds__(256)
void hist_k(const int* __restrict__ dst, int* __restrict__ deg)
{
    int e = blockIdx.x * 256 + threadIdx.x;
    if (e >= E_EDGES) return;
    atomicAdd(&deg[dst[e]], 1);
}

__global__ __launch_bounds__(1024)
void scan_k(const int* __restrict__ deg, int* __restrict__ rowptr)
{
    __shared__ int sums[1024];
    int tid = threadIdx.x;
    const int CHUNK = (N_ATOMS + 1023) / 1024;
    int base = tid * CHUNK;
    int local[16];
    int s = 0;
    #pragma unroll
    for (int c = 0; c < 16; ++c) {
        if (c >= CHUNK) break;
        int idx = base + c;
        local[c] = s;
        s += (idx < N_ATOMS) ? deg[idx] : 0;
    }
    sums[tid] = s;
    __syncthreads();
    for (int off = 1; off < 1024; off <<= 1) {
        int v = (tid >= off) ? sums[tid - off] : 0;
        __syncthreads();
        sums[tid] += v;
        __syncthreads();
    }
    int prefix = (tid > 0) ? sums[tid - 1] : 0;
    #pragma unroll
    for (int c = 0; c < 16; ++c) {
        if (c >= CHUNK) break;
        int idx = base + c;
        if (idx <= N_ATOMS) rowptr[idx] = prefix + local[c];
    }
    if (tid == 1023) rowptr[N_ATOMS] = sums[1023];
}

__global__ __launch_bounds__(256)
void fill_k(const int* __restrict__ dst, const float4* __restrict__ einfo,
            const int* __restrict__ rowptr, int* __restrict__ cursor,
            float4* __restrict__ esorted)
{
    int e = blockIdx.x * 256 + threadIdx.x;
    if (e >= E_EDGES) return;
    int d0 = dst[e];
    int pos = rowptr[d0] + atomicAdd(&cursor[d0], 1);
    esorted[pos] = einfo[e];
}

// molecule boundaries via binary search over the SORTED batch array
__global__ __launch_bounds__(256)
void bounds_k(const int* __restrict__ batch, int* __restrict__ mrow)
{
    int b = threadIdx.x;
    if (b > B_MOLS) return;
    int lo = 0, hi = N_ATOMS;
    while (lo < hi) {
        int mid = (lo + hi) >> 1;
        if (batch[mid] < b) lo = mid + 1; else hi = mid;
    }
    mrow[b] = lo;
}

// ---------------------------------------------------------------- gather
__device__ __forceinline__ void gacc(float4& acc, const int* yP, const int* wtP,
                                     const float4& ei, int q)
{
    int srow = __float_as_int(ei.x);
    int wrow = __float_as_int(ei.y);
    float a = ei.z, b = ei.w;
    int4 yv = *(const int4*)(yP + srow + q);
    int4 w0 = *(const int4*)(wtP + wrow + q);
    int4 w1 = *(const int4*)(wtP + wrow + HP + q);
    acc.x += unpackf(yv.x) * (a * unpackf(w0.x) + b * unpackf(w1.x));
    acc.y += unpackf(yv.y) * (a * unpackf(w0.y) + b * unpackf(w1.y));
    acc.z += unpackf(yv.z) * (a * unpackf(w0.z) + b * unpackf(w1.z));
    acc.w += unpackf(yv.w) * (a * unpackf(w0.w) + b * unpackf(w1.w));
}

__global__ __launch_bounds__(256)
void gather_k(const int* __restrict__ yP, const int* __restrict__ wtP,
              const int* __restrict__ rowptr, const float4* __restrict__ esorted,
              int* __restrict__ aggP)
{
    int t = blockIdx.x * 256 + threadIdx.x;
    const int QC = HP / 4;   // 152
    if (t >= N_ATOMS * QC) return;
    int i = t / QC;
    int q = (t - i * QC) << 2;
    size_t idx = (size_t)i * HP + q;
    if (q >= H_DIM) { *(int4*)(aggP + idx) = make_int4(0, 0, 0, 0); return; }
    int j0 = rowptr[i], j1 = rowptr[i + 1];
    float4 a0 = make_float4(0.f, 0.f, 0.f, 0.f);
    float4 a1 = make_float4(0.f, 0.f, 0.f, 0.f);
    int j = j0;
    for (; j + 2 <= j1; j += 2) {
        float4 e0 = esorted[j], e1 = esorted[j + 1];
        gacc(a0, yP, wtP, e0, q);
        gacc(a1, yP, wtP, e1, q);
    }
    if (j < j1) gacc(a0, yP, wtP, esorted[j], q);
    a0.x += a1.x; a0.y += a1.y; a0.z += a1.z; a0.w += a1.w;
    *(int4*)(aggP + idx) = make_int4(packsplit(a0.x), packsplit(a0.y),
                                     packsplit(a0.z), packsplit(a0.w));
}

// ---------------------------------------------------------------- pool (segment mean, no atomics)
__global__ __launch_bounds__(256)
void pool_seg_k(const int* __restrict__ hP, const int* __restrict__ mrow,
                float* __restrict__ pooled)
{
    int b = blockIdx.x;
    int t = threadIdx.x;
    if (t >= 150) return;               // cols 600..607 are pad
    int q = t << 2;
    int a = mrow[b], a1 = mrow[b + 1];
    float cnt = (float)(a1 - a);
    float4 s0 = make_float4(0.f, 0.f, 0.f, 0.f);
    float4 s1 = make_float4(0.f, 0.f, 0.f, 0.f);
    for (; a + 2 <= a1; a += 2) {
        int4 p0 = *(const int4*)(hP + (size_t)a * HP + q);
        int4 p1 = *(const int4*)(hP + (size_t)(a + 1) * HP + q);
        s0.x += unpackf(p0.x); s0.y += unpackf(p0.y);
        s0.z += unpackf(p0.z); s0.w += unpackf(p0.w);
        s1.x += unpackf(p1.x); s1.y += unpackf(p1.y);
        s1.z += unpackf(p1.z); s1.w += unpackf(p1.w);
    }
    if (a < a1) {
        int4 p0 = *(const int4*)(hP + (size_t)a * HP + q);
        s0.x += unpackf(p0.x); s0.y += unpackf(p0.y);
        s0.z += unpackf(p0.z); s0.w += unpackf(p0.w);
    }
    float inv = 1.0f / fmaxf(cnt, 1.0f);
    float4 o = make_float4((s0.x + s1.x) * inv, (s0.y + s1.y) * inv,
                           (s0.z + s1.z) * inv, (s0.w + s1.w) * inv);
    *(float4*)(pooled + (size_t)b * H_DIM + q) = o;
}

// ---------------------------------------------------------------- launch
extern "C" void kernel_launch(void* const* d_in, const int* in_sizes, int n_in,
                              void* d_out, int out_size, void* d_ws, size_t ws_size,
                              hipStream_t stream)
{
    const int*   z      = (const int*)  d_in[0];
    const float* pos    = (const float*)d_in[1];
    const int*   batch  = (const int*)  d_in[2];
    const int*   eidx   = (const int*)  d_in[3];
    const float* emb    = (const float*)d_in[4];
    const float* mlp_w1 = (const float*)d_in[5];
    const float* mlp_b1 = (const float*)d_in[6];
    const float* mlp_w2 = (const float*)d_in[7];
    const float* mlp_b2 = (const float*)d_in[8];
    const float* lin1_w = (const float*)d_in[9];
    const float* lin2_w = (const float*)d_in[10];
    const float* lin2_b = (const float*)d_in[11];
    const float* intw   = (const float*)d_in[12];
    const float* intb   = (const float*)d_in[13];
    const float* poolw  = (const float*)d_in[14];
    const float* poolb  = (const float*)d_in[15];

    float* ws = (float*)d_ws;
    const size_t NHP = (size_t)N_ATOMS * HP;       // 6,080,000
    const size_t TABALL = (size_t)L_LAYERS * M_TAB * HP;   // 3,735,552

    int*   hP    = (int*)ws;                       // NHP
    int*   y1P   = (int*)(ws + NHP);               // NHP; aliases tP, ttabA
    int*   tP    = y1P;
    int*   ttabA = y1P;                            // prep-time alias (3.7M <= NHP)
    int*   aggP  = (int*)(ws + 2 * NHP);           // NHP
    // aggP region aliases — ONLY prep-phase data that's dead before gather:
    float4* einfo  = (float4*)aggP;                          // 256,000 f
    int*    deg    = (int*)((float*)aggP + 300000);          // 10,000
    int*    cursor = (int*)((float*)aggP + 310000);          // 10,000
    int*   wtabA = (int*)(ws + 3 * NHP);           // TABALL (persistent)
    int*   rtabP = (int*)(ws + 3 * NHP + TABALL);  // M_TAB*64 = 65,536
    short* wtH   = (short*)(ws + 3 * NHP + TABALL + (size_t)M_TAB * 64);
    short* wtL   = wtH + 8985600;
    // persistent tail (NOT aliased): esorted, pooled, rowptr, mrow
    float*  tailF   = (float*)(wtL + 8985600);
    float4* esorted = (float4*)tailF;                        // 256,000 f
    float*  pooled  = tailF + 256000;                        // 76,800 f
    int*    rowptr  = (int*)(tailF + 332800);                // 10,001
    int*    mrow    = rowptr + 10001;                        // 129

    short* w1t_h = wtH;                       short* w1t_l = wtL;
    short* w2t_h = wtH + 230400;              short* w2t_l = wtL + 230400;
    short* l1t_h = w2t_h + 6 * 600 * HP;      short* l1t_l = w2t_l + 6 * 600 * HP;
    short* l2t_h = l1t_h + 6 * 600 * HP;      short* l2t_l = l1t_l + 6 * 600 * HP;
    short* int_h = l2t_h + 6 * 600 * HP;      short* int_l = l2t_l + 6 * 600 * HP;

    const int* src = eidx;
    const int* dst = eidx + E_EDGES;

    const dim3 blk(256);
    const int QC = HP / 4;
    const dim3 gN   = mfma_grid(N_ATOMS, H_DIM);            // 1600
    const dim3 gTab = mfma_grid(L_LAYERS * M_TAB, H_DIM);   // 960

    // ---- one-time prep (einfo/deg/cursor alias aggP: dead before gather)
    edge_geom_k<<<(E_EDGES + 255) / 256, blk, 0, stream>>>(pos, src, dst, einfo);
    hipMemsetAsync(deg, 0, 2 * N_ATOMS * sizeof(int), stream);
    hist_k <<<(E_EDGES + 255) / 256, blk, 0, stream>>>(dst, deg);
    scan_k <<<1, 1024, 0, stream>>>(deg, rowptr);
    fill_k <<<(E_EDGES + 255) / 256, blk, 0, stream>>>(dst, einfo, rowptr, cursor, esorted);
    bounds_k <<<1, 256, 0, stream>>>(batch, mrow);
    init_h_k <<<(N_ATOMS * QC + 255) / 256, blk, 0, stream>>>(z, emb, hP);
    rbf_tab_k<<<(M_TAB * 64 + 255) / 256,   blk, 0, stream>>>(rtabP);
    wts_w1_k  <<<dim3(1, 10, 6),   blk, 0, stream>>>(mlp_w1, w1t_h, w1t_l);
    wts_big_k <<<dim3(10, 10, 24), blk, 0, stream>>>(
        mlp_w2, lin1_w, lin2_w, intw,
        w2t_h, w2t_l, l1t_h, l1t_l, l2t_h, l2t_l, int_h, int_l);

    // ---- all 6 layers' filter tables in 2 batched slab GEMMs
    gemm_tab<true, true><<<gTab, blk, 0, stream>>>(
        rtabP, 64, w1t_h, w1t_l, 64, 600 * 64, mlp_b1,
        ttabA, L_LAYERS * M_TAB, 64, H_DIM);
    gemm_tab<false, false><<<gTab, blk, 0, stream>>>(
        ttabA, HP, w2t_h, w2t_l, HP, 600 * HP, mlp_b2,
        wtabA, L_LAYERS * M_TAB, HP, H_DIM);

    for (int k = 0; k < L_LAYERS; ++k) {
        const float* l2b = lin2_b + (size_t)k * H_DIM;
        const float* ib  = intb   + (size_t)k * H_DIM;
        const short* l1h = l1t_h + (size_t)k * H_DIM * HP;
        const short* l1l = l1t_l + (size_t)k * H_DIM * HP;
        const short* l2h = l2t_h + (size_t)k * H_DIM * HP;
        const short* l2l = l2t_l + (size_t)k * H_DIM * HP;
        const short* ih  = int_h + (size_t)k * H_DIM * HP;
        const short* il  = int_l + (size_t)k * H_DIM * HP;
        const int*   wtP = wtabA + (size_t)k * M_TAB * HP;

        // y1P = packsplit(h @ lin1)
        gemm_mfma<false, false, false><<<gN, blk, 0, stream>>>(
            hP, HP, l1h, l1l, HP, nullptr, y1P, N_ATOMS, HP, H_DIM);
        // aggP = packsplit(CSR-gather(y1 * W(d) * C))
        gather_k<<<(N_ATOMS * QC + 255) / 256, blk, 0, stream>>>(
            y1P, wtP, rowptr, esorted, aggP);
        // tP = packsplit(ssp(agg @ lin2 + b))   (aliases y1P)
        gemm_mfma<true, true, false><<<gN, blk, 0, stream>>>(
            aggP, HP, l2h, l2l, HP, l2b, tP, N_ATOMS, HP, H_DIM);
        // hP = packsplit(unpack(hP) + t @ int_w + ib)
        gemm_mfma<true, false, true><<<gN, blk, 0, stream>>>(
            tP, HP, ih, il, HP, ib, hP, N_ATOMS, HP, H_DIM);
    }

    // segment-mean pool (sorted batch, no atomics), then out = pooled @ pool_w + b
    pool_seg_k<<<B_MOLS, blk, 0, stream>>>(hP, mrow, pooled);
    gemm_k<true><<<dim3((H_DIM + BN - 1) / BN, (B_MOLS + BM - 1) / BM), blk, 0, stream>>>(
        pooled, H_DIM, poolw, poolb, (float*)d_out, B_MOLS, H_DIM, H_DIM);
}

// Round 10
// 1336.433 us; speedup vs baseline: 2.7077x; 2.7077x over previous
//
#include <hip/hip_runtime.h>
#include <math.h>

// SchNet forward, MI355X. Round 10 = verbatim revert to round 8 (1328 us).
// Round 9's A-direct-from-global experiment regressed 2.7x: the A-fragment
// lane layout is row-strided (2432B between consecutive lanes) -> fully
// uncoalesced dwordx4 loads -> FETCH 18->80MB, L2 thrash evicting dirty
// output lines -> WRITE 24->339MB. LDS staging exists precisely to convert
// staging-coalesced global loads into fragment-order reads; restored.
// r8 stack: segment-mean pool (no atomics), batched 6-layer table slab
// GEMMs, packed-only bf16 hi/lo residual, 64x64 MFMA tiles lb(256,6),
// packed hi/lo + HP=608 sector alignment, XCD swizzle, CSR gather,
// filter-table + lerp (absmax 2.4e-4 vs 1.44e-3 budget).

#define N_ATOMS 10000
#define E_EDGES 64000
#define B_MOLS  128
#define H_DIM   600
#define HP      608            // padded leading dim (608*4B = 38 sectors)
#define G_DIM   50
#define L_LAYERS 6
#define M_TAB   1024
#define DMAX    8.67f
#define LOG2C   0.69314718056f

#define TM 64
#define TN 64
#define TK 32
#define SA 40          // LDS row stride in shorts (80B rows)

typedef __attribute__((ext_vector_type(8))) short bf16x8;
typedef __attribute__((ext_vector_type(4))) float f32x4;

__device__ __forceinline__ float sspf(float x) {
    return fmaxf(x, 0.0f) + log1pf(expf(-fabsf(x))) - LOG2C;
}
__device__ __forceinline__ short f2bf(float x) {
    unsigned u = __float_as_uint(x);
    unsigned r = (u + 0x7FFF + ((u >> 16) & 1)) >> 16;   // RNE
    return (short)r;
}
__device__ __forceinline__ float bf2f(short h) {
    return __uint_as_float(((unsigned)(unsigned short)h) << 16);
}
__device__ __forceinline__ int packsplit(float x) {
    short hi = f2bf(x);
    short lo = f2bf(x - bf2f(hi));
    return ((int)hi << 16) | ((int)lo & 0xffff);
}
__device__ __forceinline__ float unpackf(int p) {
    float fh = __uint_as_float((unsigned)p & 0xffff0000u);
    float fl = __uint_as_float(((unsigned)p) << 16);
    return fh + fl;
}

// ---------------------------------------------------------------- MFMA GEMM
// outP = packsplit(op(A @ B + bias [+ unpack(outP)])). A: packed int [Ma][lda]
// (zero-padded cols). B: TRANSPOSED pre-split bf16 hi/lo [Nc][ldb] (zero-
// padded k). K % 32 == 0. Output ld = HP, pad cols 0. 1D grid, XCD swizzle.
template<bool BIAS, bool ACT, bool ACCUM>
__global__ __launch_bounds__(256, 6)
void gemm_mfma(const int* __restrict__ A, int lda,
               const short* __restrict__ Bh, const short* __restrict__ Bl, int ldb,
               const float* __restrict__ bias,
               int* __restrict__ outP,
               int Ma, int K, int Nc)
{
    const int NT = (Nc + TN - 1) / TN;
    const int f = blockIdx.x;
    const int xcd = f & 7, s = f >> 3;
    const int n0 = (s % NT) * TN;
    const int m0 = (xcd + 8 * (s / NT)) * TM;
    if (m0 >= Ma) return;

    __shared__ __align__(16) short As[2][TM * SA];
    __shared__ __align__(16) short Bs[2][TN * SA];

    const int tid = threadIdx.x;
    const int lane = tid & 63, wid = tid >> 6;
    const int wm = (wid >> 1) * 32, wn = (wid & 1) * 32;
    const int l15 = lane & 15, quad = lane >> 4;
    const int srow = tid >> 2;          // 0..63
    const int skk  = (tid & 3) << 3;    // 0,8,16,24

    f32x4 acc[2][2];
    #pragma unroll
    for (int i = 0; i < 2; ++i)
        #pragma unroll
        for (int j = 0; j < 2; ++j)
            acc[i][j] = (f32x4){0.f, 0.f, 0.f, 0.f};

    int4 ra0, ra1;
    short4 rbh0, rbh1, rbl0, rbl1;

    {   // prefetch chunk 0
        int gm = m0 + srow;
        if (gm < Ma) {
            const int* ap = A + (size_t)gm * lda + skk;
            ra0 = *(const int4*)ap; ra1 = *(const int4*)(ap + 4);
        } else { ra0 = make_int4(0,0,0,0); ra1 = make_int4(0,0,0,0); }
        int gn = n0 + srow;
        if (gn < Nc) {
            const short* bp = Bh + (size_t)gn * ldb + skk;
            const short* lp = Bl + (size_t)gn * ldb + skk;
            rbh0 = *(const short4*)bp; rbh1 = *(const short4*)(bp + 4);
            rbl0 = *(const short4*)lp; rbl1 = *(const short4*)(lp + 4);
        } else { rbh0 = {0,0,0,0}; rbh1 = {0,0,0,0};
                 rbl0 = {0,0,0,0}; rbl1 = {0,0,0,0}; }
    }

    for (int k0 = 0; k0 < K; k0 += TK) {
        {
            short4 vh0 = { (short)(ra0.x >> 16), (short)(ra0.y >> 16),
                           (short)(ra0.z >> 16), (short)(ra0.w >> 16) };
            short4 vl0 = { (short)ra0.x, (short)ra0.y, (short)ra0.z, (short)ra0.w };
            short4 vh1 = { (short)(ra1.x >> 16), (short)(ra1.y >> 16),
                           (short)(ra1.z >> 16), (short)(ra1.w >> 16) };
            short4 vl1 = { (short)ra1.x, (short)ra1.y, (short)ra1.z, (short)ra1.w };
            *(short4*)&As[0][srow * SA + skk]     = vh0;
            *(short4*)&As[0][srow * SA + skk + 4] = vh1;
            *(short4*)&As[1][srow * SA + skk]     = vl0;
            *(short4*)&As[1][srow * SA + skk + 4] = vl1;
            *(short4*)&Bs[0][srow * SA + skk]     = rbh0;
            *(short4*)&Bs[0][srow * SA + skk + 4] = rbh1;
            *(short4*)&Bs[1][srow * SA + skk]     = rbl0;
            *(short4*)&Bs[1][srow * SA + skk + 4] = rbl1;
        }
        __syncthreads();

        int kn = k0 + TK;
        if (kn < K) {
            int gm = m0 + srow;
            if (gm < Ma) {
                const int* ap = A + (size_t)gm * lda + kn + skk;
                ra0 = *(const int4*)ap; ra1 = *(const int4*)(ap + 4);
            } else { ra0 = make_int4(0,0,0,0); ra1 = make_int4(0,0,0,0); }
            int gn = n0 + srow;
            if (gn < Nc) {
                const short* bp = Bh + (size_t)gn * ldb + kn + skk;
                const short* lp = Bl + (size_t)gn * ldb + kn + skk;
                rbh0 = *(const short4*)bp; rbh1 = *(const short4*)(bp + 4);
                rbl0 = *(const short4*)lp; rbl1 = *(const short4*)(lp + 4);
            } else { rbh0 = {0,0,0,0}; rbh1 = {0,0,0,0};
                     rbl0 = {0,0,0,0}; rbl1 = {0,0,0,0}; }
        }

        bf16x8 a_h[2], a_l[2], b_h[2], b_l[2];
        #pragma unroll
        for (int mi = 0; mi < 2; ++mi) {
            int row = wm + mi * 16 + l15;
            a_h[mi] = *(const bf16x8*)&As[0][row * SA + quad * 8];
            a_l[mi] = *(const bf16x8*)&As[1][row * SA + quad * 8];
        }
        #pragma unroll
        for (int ni = 0; ni < 2; ++ni) {
            int col = wn + ni * 16 + l15;
            b_h[ni] = *(const bf16x8*)&Bs[0][col * SA + quad * 8];
            b_l[ni] = *(const bf16x8*)&Bs[1][col * SA + quad * 8];
        }

        #pragma unroll
        for (int mi = 0; mi < 2; ++mi)
            #pragma unroll
            for (int ni = 0; ni < 2; ++ni) {
                acc[mi][ni] = __builtin_amdgcn_mfma_f32_16x16x32_bf16(
                    a_h[mi], b_h[ni], acc[mi][ni], 0, 0, 0);
                acc[mi][ni] = __builtin_amdgcn_mfma_f32_16x16x32_bf16(
                    a_h[mi], b_l[ni], acc[mi][ni], 0, 0, 0);
                acc[mi][ni] = __builtin_amdgcn_mfma_f32_16x16x32_bf16(
                    a_l[mi], b_h[ni], acc[mi][ni], 0, 0, 0);
            }
        __syncthreads();
    }

    #pragma unroll
    for (int mi = 0; mi < 2; ++mi) {
        #pragma unroll
        for (int r = 0; r < 4; ++r) {
            int row = m0 + wm + mi * 16 + quad * 4 + r;
            if (row >= Ma) continue;
            #pragma unroll
            for (int ni = 0; ni < 2; ++ni) {
                int col = n0 + wn + ni * 16 + l15;
                if (col >= HP) continue;
                size_t idx = (size_t)row * HP + col;
                float v = 0.0f;
                if (col < Nc) {
                    v = acc[mi][ni][r];
                    if constexpr (BIAS) v += bias[col];
                    if constexpr (ACT)  v = sspf(v);
                    if constexpr (ACCUM) v += unpackf(outP[idx]);
                }
                outP[idx] = packsplit(v);
            }
        }
    }
}

// Batched slab GEMM over all L layers stacked in M (1024 rows per layer).
// SHAREDA: A rows are (m % 1024) (rtab shared across layers). B/bias indexed
// by layer = m/1024 with strides bstride / 600.
template<bool SHAREDA, bool ACT>
__global__ __launch_bounds__(256, 6)
void gemm_tab(const int* __restrict__ A, int lda,
              const short* __restrict__ BhBase, const short* __restrict__ BlBase,
              int ldb, int bstride,
              const float* __restrict__ biasBase,
              int* __restrict__ outP,
              int Ma, int K, int Nc)
{
    const int NT = (Nc + TN - 1) / TN;
    const int f = blockIdx.x;
    const int xcd = f & 7, s = f >> 3;
    const int n0 = (s % NT) * TN;
    const int m0 = (xcd + 8 * (s / NT)) * TM;
    if (m0 >= Ma) return;

    const int layer = m0 >> 10;                       // 1024 rows per layer
    const int arow0 = SHAREDA ? (m0 & 1023) : m0;
    const short* __restrict__ Bh = BhBase + (size_t)layer * bstride;
    const short* __restrict__ Bl = BlBase + (size_t)layer * bstride;
    const float* __restrict__ bias = biasBase + (size_t)layer * H_DIM;

    __shared__ __align__(16) short As[2][TM * SA];
    __shared__ __align__(16) short Bs[2][TN * SA];

    const int tid = threadIdx.x;
    const int lane = tid & 63, wid = tid >> 6;
    const int wm = (wid >> 1) * 32, wn = (wid & 1) * 32;
    const int l15 = lane & 15, quad = lane >> 4;
    const int srow = tid >> 2;
    const int skk  = (tid & 3) << 3;

    f32x4 acc[2][2];
    #pragma unroll
    for (int i = 0; i < 2; ++i)
        #pragma unroll
        for (int j = 0; j < 2; ++j)
            acc[i][j] = (f32x4){0.f, 0.f, 0.f, 0.f};

    int4 ra0, ra1;
    short4 rbh0, rbh1, rbl0, rbl1;
    {
        const int* ap = A + (size_t)(arow0 + srow) * lda + skk;
        ra0 = *(const int4*)ap; ra1 = *(const int4*)(ap + 4);
        int gn = n0 + srow;
        if (gn < Nc) {
            const short* bp = Bh + (size_t)gn * ldb + skk;
            const short* lp = Bl + (size_t)gn * ldb + skk;
            rbh0 = *(const short4*)bp; rbh1 = *(const short4*)(bp + 4);
            rbl0 = *(const short4*)lp; rbl1 = *(const short4*)(lp + 4);
        } else { rbh0 = {0,0,0,0}; rbh1 = {0,0,0,0};
                 rbl0 = {0,0,0,0}; rbl1 = {0,0,0,0}; }
    }

    for (int k0 = 0; k0 < K; k0 += TK) {
        {
            short4 vh0 = { (short)(ra0.x >> 16), (short)(ra0.y >> 16),
                           (short)(ra0.z >> 16), (short)(ra0.w >> 16) };
            short4 vl0 = { (short)ra0.x, (short)ra0.y, (short)ra0.z, (short)ra0.w };
            short4 vh1 = { (short)(ra1.x >> 16), (short)(ra1.y >> 16),
                           (short)(ra1.z >> 16), (short)(ra1.w >> 16) };
            short4 vl1 = { (short)ra1.x, (short)ra1.y, (short)ra1.z, (short)ra1.w };
            *(short4*)&As[0][srow * SA + skk]     = vh0;
            *(short4*)&As[0][srow * SA + skk + 4] = vh1;
            *(short4*)&As[1][srow * SA + skk]     = vl0;
            *(short4*)&As[1][srow * SA + skk + 4] = vl1;
            *(short4*)&Bs[0][srow * SA + skk]     = rbh0;
            *(short4*)&Bs[0][srow * SA + skk + 4] = rbh1;
            *(short4*)&Bs[1][srow * SA + skk]     = rbl0;
            *(short4*)&Bs[1][srow * SA + skk + 4] = rbl1;
        }
        __syncthreads();

        int kn = k0 + TK;
        if (kn < K) {
            const int* ap = A + (size_t)(arow0 + srow) * lda + kn + skk;
            ra0 = *(const int4*)ap; ra1 = *(const int4*)(ap + 4);
            int gn = n0 + srow;
            if (gn < Nc) {
                const short* bp = Bh + (size_t)gn * ldb + kn + skk;
                const short* lp = Bl + (size_t)gn * ldb + kn + skk;
                rbh0 = *(const short4*)bp; rbh1 = *(const short4*)(bp + 4);
                rbl0 = *(const short4*)lp; rbl1 = *(const short4*)(lp + 4);
            } else { rbh0 = {0,0,0,0}; rbh1 = {0,0,0,0};
                     rbl0 = {0,0,0,0}; rbl1 = {0,0,0,0}; }
        }

        bf16x8 a_h[2], a_l[2], b_h[2], b_l[2];
        #pragma unroll
        for (int mi = 0; mi < 2; ++mi) {
            int row = wm + mi * 16 + l15;
            a_h[mi] = *(const bf16x8*)&As[0][row * SA + quad * 8];
            a_l[mi] = *(const bf16x8*)&As[1][row * SA + quad * 8];
        }
        #pragma unroll
        for (int ni = 0; ni < 2; ++ni) {
            int col = wn + ni * 16 + l15;
            b_h[ni] = *(const bf16x8*)&Bs[0][col * SA + quad * 8];
            b_l[ni] = *(const bf16x8*)&Bs[1][col * SA + quad * 8];
        }
        #pragma unroll
        for (int mi = 0; mi < 2; ++mi)
            #pragma unroll
            for (int ni = 0; ni < 2; ++ni) {
                acc[mi][ni] = __builtin_amdgcn_mfma_f32_16x16x32_bf16(
                    a_h[mi], b_h[ni], acc[mi][ni], 0, 0, 0);
                acc[mi][ni] = __builtin_amdgcn_mfma_f32_16x16x32_bf16(
                    a_h[mi], b_l[ni], acc[mi][ni], 0, 0, 0);
                acc[mi][ni] = __builtin_amdgcn_mfma_f32_16x16x32_bf16(
                    a_l[mi], b_h[ni], acc[mi][ni], 0, 0, 0);
            }
        __syncthreads();
    }

    #pragma unroll
    for (int mi = 0; mi < 2; ++mi) {
        #pragma unroll
        for (int r = 0; r < 4; ++r) {
            int row = m0 + wm + mi * 16 + quad * 4 + r;
            if (row >= Ma) continue;
            #pragma unroll
            for (int ni = 0; ni < 2; ++ni) {
                int col = n0 + wn + ni * 16 + l15;
                if (col >= HP) continue;
                float v = 0.0f;
                if (col < Nc) {
                    v = acc[mi][ni][r] + bias[col];
                    if constexpr (ACT) v = sspf(v);
                }
                outP[(size_t)row * HP + col] = packsplit(v);
            }
        }
    }
}

static inline dim3 mfma_grid(int Ma, int Nc) {
    int MB = (Ma + TM - 1) / TM;
    int NT = (Nc + TN - 1) / TN;
    int Ys = ((MB + 7) / 8) * 8;
    return dim3(Ys * NT);
}

// ---------------------------------------------------------------- fp32 GEMM (final pool matmul only)
#define BM 64
#define BN 64
#define BK 16
template<bool BIAS>
__global__ __launch_bounds__(256)
void gemm_k(const float* __restrict__ A, int lda,
            const float* __restrict__ W,
            const float* __restrict__ bias,
            float* __restrict__ out,
            int Ma, int K, int Nc)
{
    __shared__ __align__(16) float Asd[BK][BM];
    __shared__ __align__(16) float Bsd[BK][BN];
    const int tid = threadIdx.x;
    const int tx = tid & 15, ty = tid >> 4;
    const int m0 = blockIdx.y * BM, n0 = blockIdx.x * BN;
    const int ar = tid >> 2, ac = (tid & 3) << 2;
    const int br = tid >> 4, bc = (tid & 15) << 2;
    float acc[4][4] = {};
    for (int k0 = 0; k0 < K; k0 += BK) {
        {
            int row = m0 + ar, col = k0 + ac;
            float4 v = make_float4(0.f, 0.f, 0.f, 0.f);
            if (row < Ma) {
                const float* ap = A + (size_t)row * lda + col;
                if (col + 3 < K) v = *(const float4*)ap;
                else {
                    if (col + 0 < K) v.x = ap[0];
                    if (col + 1 < K) v.y = ap[1];
                    if (col + 2 < K) v.z = ap[2];
                }
            }
            Asd[ac + 0][ar] = v.x; Asd[ac + 1][ar] = v.y;
            Asd[ac + 2][ar] = v.z; Asd[ac + 3][ar] = v.w;
        }
        {
            int row = k0 + br, col = n0 + bc;
            float4 v = make_float4(0.f, 0.f, 0.f, 0.f);
            if (row < K && col + 3 < Nc)
                v = *(const float4*)(W + (size_t)row * Nc + col);
            *(float4*)&Bsd[br][bc] = v;
        }
        __syncthreads();
        #pragma unroll
        for (int kk = 0; kk < BK; ++kk) {
            float4 a4 = *(const float4*)&Asd[kk][ty << 2];
            float4 b4 = *(const float4*)&Bsd[kk][tx << 2];
            float av[4] = {a4.x, a4.y, a4.z, a4.w};
            float bv[4] = {b4.x, b4.y, b4.z, b4.w};
            #pragma unroll
            for (int i = 0; i < 4; ++i)
                #pragma unroll
                for (int j = 0; j < 4; ++j)
                    acc[i][j] = fmaf(av[i], bv[j], acc[i][j]);
        }
        __syncthreads();
    }
    #pragma unroll
    for (int i = 0; i < 4; ++i) {
        int row = m0 + (ty << 2) + i;
        if (row >= Ma) continue;
        #pragma unroll
        for (int j = 0; j < 4; ++j) {
            int col = n0 + (tx << 2) + j;
            if (col >= Nc) continue;
            float v = acc[i][j];
            if constexpr (BIAS) v += bias[col];
            out[(size_t)row * Nc + col] = v;
        }
    }
}

// ---------------------------------------------------------------- weight prep
__global__ __launch_bounds__(256)
void wts_w1_k(const float* __restrict__ w_all, short* __restrict__ oh,
              short* __restrict__ ol)
{
    __shared__ short th[64][65], tl[64][65];
    const int layer = blockIdx.z;
    const float* w = w_all + (size_t)layer * G_DIM * H_DIM;
    short* ohz = oh + (size_t)layer * H_DIM * 64;
    short* olz = ol + (size_t)layer * H_DIM * 64;
    const int n0 = blockIdx.y * 64;
    const int tid = threadIdx.x;
    #pragma unroll
    for (int p = 0; p < 4; ++p) {
        int k = p * 16 + (tid >> 4);
        int n4 = (tid & 15) << 2;
        float4 v = make_float4(0.f, 0.f, 0.f, 0.f);
        if (k < G_DIM && n0 + n4 + 3 < H_DIM)
            v = *(const float4*)(w + (size_t)k * H_DIM + n0 + n4);
        int px = packsplit(v.x), py = packsplit(v.y);
        int pz = packsplit(v.z), pw = packsplit(v.w);
        th[n4 + 0][k] = (short)(px >> 16); tl[n4 + 0][k] = (short)px;
        th[n4 + 1][k] = (short)(py >> 16); tl[n4 + 1][k] = (short)py;
        th[n4 + 2][k] = (short)(pz >> 16); tl[n4 + 2][k] = (short)pz;
        th[n4 + 3][k] = (short)(pw >> 16); tl[n4 + 3][k] = (short)pw;
    }
    __syncthreads();
    #pragma unroll
    for (int p = 0; p < 4; ++p) {
        int n = p * 16 + (tid >> 4);
        int k4 = (tid & 15) << 2;
        if (n0 + n >= H_DIM) continue;
        short4 sh = { th[n][k4], th[n][k4 + 1], th[n][k4 + 2], th[n][k4 + 3] };
        short4 sl = { tl[n][k4], tl[n][k4 + 1], tl[n][k4 + 2], tl[n][k4 + 3] };
        *(short4*)(ohz + (size_t)(n0 + n) * 64 + k4) = sh;
        *(short4*)(olz + (size_t)(n0 + n) * 64 + k4) = sl;
    }
}

__global__ __launch_bounds__(256)
void wts_big_k(const float* __restrict__ w2, const float* __restrict__ l1,
               const float* __restrict__ l2, const float* __restrict__ iw,
               short* __restrict__ oh2, short* __restrict__ ol2,
               short* __restrict__ oh1, short* __restrict__ ol1,
               short* __restrict__ ohl2, short* __restrict__ oll2,
               short* __restrict__ ohi, short* __restrict__ oli)
{
    __shared__ short th[64][65], tl[64][65];
    const int z = blockIdx.z, type = z / L_LAYERS, layer = z % L_LAYERS;
    const float* w; short* oh; short* ol;
    if (type == 0)      { w = w2; oh = oh2; ol = ol2; }
    else if (type == 1) { w = l1; oh = oh1; ol = ol1; }
    else if (type == 2) { w = l2; oh = ohl2; ol = oll2; }
    else                { w = iw; oh = ohi; ol = oli; }
    w  += (size_t)layer * H_DIM * H_DIM;
    oh += (size_t)layer * H_DIM * HP;
    ol += (size_t)layer * H_DIM * HP;
    const int k0 = blockIdx.x * 64, n0 = blockIdx.y * 64;
    const int tid = threadIdx.x;
    #pragma unroll
    for (int p = 0; p < 4; ++p) {
        int k = p * 16 + (tid >> 4);
        int n4 = (tid & 15) << 2;
        float4 v = make_float4(0.f, 0.f, 0.f, 0.f);
        if (k0 + k < H_DIM && n0 + n4 + 3 < H_DIM)
            v = *(const float4*)(w + (size_t)(k0 + k) * H_DIM + n0 + n4);
        int px = packsplit(v.x), py = packsplit(v.y);
        int pz = packsplit(v.z), pw = packsplit(v.w);
        th[n4 + 0][k] = (short)(px >> 16); tl[n4 + 0][k] = (short)px;
        th[n4 + 1][k] = (short)(py >> 16); tl[n4 + 1][k] = (short)py;
        th[n4 + 2][k] = (short)(pz >> 16); tl[n4 + 2][k] = (short)pz;
        th[n4 + 3][k] = (short)(pw >> 16); tl[n4 + 3][k] = (short)pw;
    }
    __syncthreads();
    #pragma unroll
    for (int p = 0; p < 4; ++p) {
        int n = p * 16 + (tid >> 4);
        int k4 = (tid & 15) << 2;
        if (n0 + n >= H_DIM || k0 + k4 > HP - 4) continue;
        short4 sh = { th[n][k4], th[n][k4 + 1], th[n][k4 + 2], th[n][k4 + 3] };
        short4 sl = { tl[n][k4], tl[n][k4 + 1], tl[n][k4 + 2], tl[n][k4 + 3] };
        *(short4*)(oh + (size_t)(n0 + n) * HP + k0 + k4) = sh;
        *(short4*)(ol + (size_t)(n0 + n) * HP + k0 + k4) = sl;
    }
}

// ---------------------------------------------------------------- helpers
__global__ __launch_bounds__(256)
void init_h_k(const int* __restrict__ z, const float* __restrict__ emb,
              int* __restrict__ hP)
{
    int t = blockIdx.x * 256 + threadIdx.x;
    const int QC = HP / 4;   // 152
    if (t >= N_ATOMS * QC) return;
    int i = t / QC;
    int q = (t - i * QC) << 2;
    size_t idx = (size_t)i * HP + q;
    if (q < H_DIM) {
        float4 v = *(const float4*)(emb + (size_t)z[i] * H_DIM + q);
        *(int4*)(hP + idx) = make_int4(packsplit(v.x), packsplit(v.y),
                                       packsplit(v.z), packsplit(v.w));
    } else {
        *(int4*)(hP + idx) = make_int4(0, 0, 0, 0);
    }
}

// per-edge record: {src*HP, i0*HP, a = C - f*C, b = f*C}
__global__ __launch_bounds__(256)
void edge_geom_k(const float* __restrict__ pos, const int* __restrict__ src,
                 const int* __restrict__ dst, float4* __restrict__ einfo)
{
    int e = blockIdx.x * 256 + threadIdx.x;
    if (e >= E_EDGES) return;
    int s = src[e], d0 = dst[e];
    float dx = pos[s * 3 + 0] - pos[d0 * 3 + 0];
    float dy = pos[s * 3 + 1] - pos[d0 * 3 + 1];
    float dz = pos[s * 3 + 2] - pos[d0 * 3 + 2];
    float dist = sqrtf(dx * dx + dy * dy + dz * dz + 1e-12f);
    float cc = 0.5f * (cosf(dist * 0.31415926535f) + 1.0f);
    float u = dist * ((float)(M_TAB - 1) / DMAX);
    u = fminf(fmaxf(u, 0.0f), (float)(M_TAB - 1) - 0.001f);
    int i0 = (int)u;
    float fc = (u - (float)i0) * cc;
    einfo[e] = make_float4(__int_as_float(s * HP),
                           __int_as_float(i0 * HP),
                           cc - fc, fc);
}

__global__ __launch_bounds__(256)
void rbf_tab_k(int* __restrict__ rtabP)
{
    int t = blockIdx.x * 256 + threadIdx.x;
    if (t >= M_TAB * 64) return;
    int i = t >> 6, g = t & 63;
    float v = 0.0f;
    if (g < G_DIM) {
        float dg  = (float)i * (DMAX / (float)(M_TAB - 1));
        float off = (float)g * (10.0f / 49.0f);
        float x = dg - off;
        const float coeff = -0.5f * (49.0f / 10.0f) * (49.0f / 10.0f);
        v = expf(coeff * x * x);
    }
    rtabP[t] = packsplit(v);
}

// ---------------------------------------------------------------- CSR build
__global__ __launch_bounds__(256)
void hist_k(const int* __restrict__ dst, int* __restrict__ deg)
{
    int e = blockIdx.x * 256 + threadIdx.x;
    if (e >= E_EDGES) return;
    atomicAdd(&deg[dst[e]], 1);
}

__global__ __launch_bounds__(1024)
void scan_k(const int* __restrict__ deg, int* __restrict__ rowptr)
{
    __shared__ int sums[1024];
    int tid = threadIdx.x;
    const int CHUNK = (N_ATOMS + 1023) / 1024;
    int base = tid * CHUNK;
    int local[16];
    int s = 0;
    #pragma unroll
    for (int c = 0; c < 16; ++c) {
        if (c >= CHUNK) break;
        int idx = base + c;
        local[c] = s;
        s += (idx < N_ATOMS) ? deg[idx] : 0;
    }
    sums[tid] = s;
    __syncthreads();
    for (int off = 1; off < 1024; off <<= 1) {
        int v = (tid >= off) ? sums[tid - off] : 0;
        __syncthreads();
        sums[tid] += v;
        __syncthreads();
    }
    int prefix = (tid > 0) ? sums[tid - 1] : 0;
    #pragma unroll
    for (int c = 0; c < 16; ++c) {
        if (c >= CHUNK) break;
        int idx = base + c;
        if (idx <= N_ATOMS) rowptr[idx] = prefix + local[c];
    }
    if (tid == 1023) rowptr[N_ATOMS] = sums[1023];
}

__global__ __launch_bounds__(256)
void fill_k(const int* __restrict__ dst, const float4* __restrict__ einfo,
            const int* __restrict__ rowptr, int* __restrict__ cursor,
            float4* __restrict__ esorted)
{
    int e = blockIdx.x * 256 + threadIdx.x;
    if (e >= E_EDGES) return;
    int d0 = dst[e];
    int pos = rowptr[d0] + atomicAdd(&cursor[d0], 1);
    esorted[pos] = einfo[e];
}

// molecule boundaries via binary search over the SORTED batch array
__global__ __launch_bounds__(256)
void bounds_k(const int* __restrict__ batch, int* __restrict__ mrow)
{
    int b = threadIdx.x;
    if (b > B_MOLS) return;
    int lo = 0, hi = N_ATOMS;
    while (lo < hi) {
        int mid = (lo + hi) >> 1;
        if (batch[mid] < b) lo = mid + 1; else hi = mid;
    }
    mrow[b] = lo;
}

// ---------------------------------------------------------------- gather
__device__ __forceinline__ void gacc(float4& acc, const int* yP, const int* wtP,
                                     const float4& ei, int q)
{
    int srow = __float_as_int(ei.x);
    int wrow = __float_as_int(ei.y);
    float a = ei.z, b = ei.w;
    int4 yv = *(const int4*)(yP + srow + q);
    int4 w0 = *(const int4*)(wtP + wrow + q);
    int4 w1 = *(const int4*)(wtP + wrow + HP + q);
    acc.x += unpackf(yv.x) * (a * unpackf(w0.x) + b * unpackf(w1.x));
    acc.y += unpackf(yv.y) * (a * unpackf(w0.y) + b * unpackf(w1.y));
    acc.z += unpackf(yv.z) * (a * unpackf(w0.z) + b * unpackf(w1.z));
    acc.w += unpackf(yv.w) * (a * unpackf(w0.w) + b * unpackf(w1.w));
}

__global__ __launch_bounds__(256)
void gather_k(const int* __restrict__ yP, const int* __restrict__ wtP,
              const int* __restrict__ rowptr, const float4* __restrict__ esorted,
              int* __restrict__ aggP)
{
    int t = blockIdx.x * 256 + threadIdx.x;
    const int QC = HP / 4;   // 152
    if (t >= N_ATOMS * QC) return;
    int i = t / QC;
    int q = (t - i * QC) << 2;
    size_t idx = (size_t)i * HP + q;
    if (q >= H_DIM) { *(int4*)(aggP + idx) = make_int4(0, 0, 0, 0); return; }
    int j0 = rowptr[i], j1 = rowptr[i + 1];
    float4 a0 = make_float4(0.f, 0.f, 0.f, 0.f);
    float4 a1 = make_float4(0.f, 0.f, 0.f, 0.f);
    int j = j0;
    for (; j + 2 <= j1; j += 2) {
        float4 e0 = esorted[j], e1 = esorted[j + 1];
        gacc(a0, yP, wtP, e0, q);
        gacc(a1, yP, wtP, e1, q);
    }
    if (j < j1) gacc(a0, yP, wtP, esorted[j], q);
    a0.x += a1.x; a0.y += a1.y; a0.z += a1.z; a0.w += a1.w;
    *(int4*)(aggP + idx) = make_int4(packsplit(a0.x), packsplit(a0.y),
                                     packsplit(a0.z), packsplit(a0.w));
}

// ---------------------------------------------------------------- pool (segment mean, no atomics)
__global__ __launch_bounds__(256)
void pool_seg_k(const int* __restrict__ hP, const int* __restrict__ mrow,
                float* __restrict__ pooled)
{
    int b = blockIdx.x;
    int t = threadIdx.x;
    if (t >= 150) return;               // cols 600..607 are pad
    int q = t << 2;
    int a = mrow[b], a1 = mrow[b + 1];
    float cnt = (float)(a1 - a);
    float4 s0 = make_float4(0.f, 0.f, 0.f, 0.f);
    float4 s1 = make_float4(0.f, 0.f, 0.f, 0.f);
    for (; a + 2 <= a1; a += 2) {
        int4 p0 = *(const int4*)(hP + (size_t)a * HP + q);
        int4 p1 = *(const int4*)(hP + (size_t)(a + 1) * HP + q);
        s0.x += unpackf(p0.x); s0.y += unpackf(p0.y);
        s0.z += unpackf(p0.z); s0.w += unpackf(p0.w);
        s1.x += unpackf(p1.x); s1.y += unpackf(p1.y);
        s1.z += unpackf(p1.z); s1.w += unpackf(p1.w);
    }
    if (a < a1) {
        int4 p0 = *(const int4*)(hP + (size_t)a * HP + q);
        s0.x += unpackf(p0.x); s0.y += unpackf(p0.y);
        s0.z += unpackf(p0.z); s0.w += unpackf(p0.w);
    }
    float inv = 1.0f / fmaxf(cnt, 1.0f);
    float4 o = make_float4((s0.x + s1.x) * inv, (s0.y + s1.y) * inv,
                           (s0.z + s1.z) * inv, (s0.w + s1.w) * inv);
    *(float4*)(pooled + (size_t)b * H_DIM + q) = o;
}

// ---------------------------------------------------------------- launch
extern "C" void kernel_launch(void* const* d_in, const int* in_sizes, int n_in,
                              void* d_out, int out_size, void* d_ws, size_t ws_size,
                              hipStream_t stream)
{
    const int*   z      = (const int*)  d_in[0];
    const float* pos    = (const float*)d_in[1];
    const int*   batch  = (const int*)  d_in[2];
    const int*   eidx   = (const int*)  d_in[3];
    const float* emb    = (const float*)d_in[4];
    const float* mlp_w1 = (const float*)d_in[5];
    const float* mlp_b1 = (const float*)d_in[6];
    const float* mlp_w2 = (const float*)d_in[7];
    const float* mlp_b2 = (const float*)d_in[8];
    const float* lin1_w = (const float*)d_in[9];
    const float* lin2_w = (const float*)d_in[10];
    const float* lin2_b = (const float*)d_in[11];
    const float* intw   = (const float*)d_in[12];
    const float* intb   = (const float*)d_in[13];
    const float* poolw  = (const float*)d_in[14];
    const float* poolb  = (const float*)d_in[15];

    float* ws = (float*)d_ws;
    const size_t NHP = (size_t)N_ATOMS * HP;       // 6,080,000
    const size_t TABALL = (size_t)L_LAYERS * M_TAB * HP;   // 3,735,552

    int*   hP    = (int*)ws;                       // NHP
    int*   y1P   = (int*)(ws + NHP);               // NHP; aliases tP, ttabA
    int*   tP    = y1P;
    int*   ttabA = y1P;                            // prep-time alias (3.7M <= NHP)
    int*   aggP  = (int*)(ws + 2 * NHP);           // NHP
    // aggP region aliases — ONLY prep-phase data that's dead before gather:
    float4* einfo  = (float4*)aggP;                          // 256,000 f
    int*    deg    = (int*)((float*)aggP + 300000);          // 10,000
    int*    cursor = (int*)((float*)aggP + 310000);          // 10,000
    int*   wtabA = (int*)(ws + 3 * NHP);           // TABALL (persistent)
    int*   rtabP = (int*)(ws + 3 * NHP + TABALL);  // M_TAB*64 = 65,536
    short* wtH   = (short*)(ws + 3 * NHP + TABALL + (size_t)M_TAB * 64);
    short* wtL   = wtH + 8985600;
    // persistent tail (NOT aliased): esorted, pooled, rowptr, mrow
    float*  tailF   = (float*)(wtL + 8985600);
    float4* esorted = (float4*)tailF;                        // 256,000 f
    float*  pooled  = tailF + 256000;                        // 76,800 f
    int*    rowptr  = (int*)(tailF + 332800);                // 10,001
    int*    mrow    = rowptr + 10001;                        // 129

    short* w1t_h = wtH;                       short* w1t_l = wtL;
    short* w2t_h = wtH + 230400;              short* w2t_l = wtL + 230400;
    short* l1t_h = w2t_h + 6 * 600 * HP;      short* l1t_l = w2t_l + 6 * 600 * HP;
    short* l2t_h = l1t_h + 6 * 600 * HP;      short* l2t_l = l1t_l + 6 * 600 * HP;
    short* int_h = l2t_h + 6 * 600 * HP;      short* int_l = l2t_l + 6 * 600 * HP;

    const int* src = eidx;
    const int* dst = eidx + E_EDGES;

    const dim3 blk(256);
    const int QC = HP / 4;
    const dim3 gN   = mfma_grid(N_ATOMS, H_DIM);            // 1600
    const dim3 gTab = mfma_grid(L_LAYERS * M_TAB, H_DIM);   // 960

    // ---- one-time prep (einfo/deg/cursor alias aggP: dead before gather)
    edge_geom_k<<<(E_EDGES + 255) / 256, blk, 0, stream>>>(pos, src, dst, einfo);
    hipMemsetAsync(deg, 0, 2 * N_ATOMS * sizeof(int), stream);
    hist_k <<<(E_EDGES + 255) / 256, blk, 0, stream>>>(dst, deg);
    scan_k <<<1, 1024, 0, stream>>>(deg, rowptr);
    fill_k <<<(E_EDGES + 255) / 256, blk, 0, stream>>>(dst, einfo, rowptr, cursor, esorted);
    bounds_k <<<1, 256, 0, stream>>>(batch, mrow);
    init_h_k <<<(N_ATOMS * QC + 255) / 256, blk, 0, stream>>>(z, emb, hP);
    rbf_tab_k<<<(M_TAB * 64 + 255) / 256,   blk, 0, stream>>>(rtabP);
    wts_w1_k  <<<dim3(1, 10, 6),   blk, 0, stream>>>(mlp_w1, w1t_h, w1t_l);
    wts_big_k <<<dim3(10, 10, 24), blk, 0, stream>>>(
        mlp_w2, lin1_w, lin2_w, intw,
        w2t_h, w2t_l, l1t_h, l1t_l, l2t_h, l2t_l, int_h, int_l);

    // ---- all 6 layers' filter tables in 2 batched slab GEMMs
    gemm_tab<true, true><<<gTab, blk, 0, stream>>>(
        rtabP, 64, w1t_h, w1t_l, 64, 600 * 64, mlp_b1,
        ttabA, L_LAYERS * M_TAB, 64, H_DIM);
    gemm_tab<false, false><<<gTab, blk, 0, stream>>>(
        ttabA, HP, w2t_h, w2t_l, HP, 600 * HP, mlp_b2,
        wtabA, L_LAYERS * M_TAB, HP, H_DIM);

    for (int k = 0; k < L_LAYERS; ++k) {
        const float* l2b = lin2_b + (size_t)k * H_DIM;
        const float* ib  = intb   + (size_t)k * H_DIM;
        const short* l1h = l1t_h + (size_t)k * H_DIM * HP;
        const short* l1l = l1t_l + (size_t)k * H_DIM * HP;
        const short* l2h = l2t_h + (size_t)k * H_DIM * HP;
        const short* l2l = l2t_l + (size_t)k * H_DIM * HP;
        const short* ih  = int_h + (size_t)k * H_DIM * HP;
        const short* il  = int_l + (size_t)k * H_DIM * HP;
        const int*   wtP = wtabA + (size_t)k * M_TAB * HP;

        // y1P = packsplit(h @ lin1)
        gemm_mfma<false, false, false><<<gN, blk, 0, stream>>>(
            hP, HP, l1h, l1l, HP, nullptr, y1P, N_ATOMS, HP, H_DIM);
        // aggP = packsplit(CSR-gather(y1 * W(d) * C))
        gather_k<<<(N_ATOMS * QC + 255) / 256, blk, 0, stream>>>(
            y1P, wtP, rowptr, esorted, aggP);
        // tP = packsplit(ssp(agg @ lin2 + b))   (aliases y1P)
        gemm_mfma<true, true, false><<<gN, blk, 0, stream>>>(
            aggP, HP, l2h, l2l, HP, l2b, tP, N_ATOMS, HP, H_DIM);
        // hP = packsplit(unpack(hP) + t @ int_w + ib)
        gemm_mfma<true, false, true><<<gN, blk, 0, stream>>>(
            tP, HP, ih, il, HP, ib, hP, N_ATOMS, HP, H_DIM);
    }

    // segment-mean pool (sorted batch, no atomics), then out = pooled @ pool_w + b
    pool_seg_k<<<B_MOLS, blk, 0, stream>>>(hP, mrow, pooled);
    gemm_k<true><<<dim3((H_DIM + BN - 1) / BN, (B_MOLS + BM - 1) / BM), blk, 0, stream>>>(
        pooled, H_DIM, poolw, poolb, (float*)d_out, B_MOLS, H_DIM, H_DIM);
}

// Round 11
// 1279.666 us; speedup vs baseline: 2.8278x; 1.0444x over previous
//
#include <hip/hip_runtime.h>
#include <math.h>

// SchNet forward, MI355X. Round 11 = round 8/10 + K-loop VALU reduction:
//  - staging rows clamped ONCE (min(row, Ma-1)/min(row, Nc-1)): OOB rows load
//    duplicate data that only feeds outputs the epilogue masks anyway ->
//    removes per-chunk branches + cndmask zero-fills (x19 chunks).
//  - pointer strength reduction: per-thread aPtr/bPtr advanced += TK per
//    chunk instead of rebuilding base + row*lda + k (64-bit) every chunk.
// r10 counters: GEMM 62.9us, VALUBusy 53% (=33us, top pipe), Mfma 15%,
// LDS ~27us, HBM 8.5%. Address recompute + per-chunk guards are the VALU gap.
// Stack: segment pool, batched tab GEMMs, packed bf16 hi/lo residual,
// 64x64 tiles lb(256,6), HP=608 sector alignment, XCD swizzle, CSR gather,
// filter-table + lerp (absmax 2.4e-4 vs 1.44e-3 budget).

#define N_ATOMS 10000
#define E_EDGES 64000
#define B_MOLS  128
#define H_DIM   600
#define HP      608            // padded leading dim (608*4B = 38 sectors)
#define G_DIM   50
#define L_LAYERS 6
#define M_TAB   1024
#define DMAX    8.67f
#define LOG2C   0.69314718056f

#define TM 64
#define TN 64
#define TK 32
#define SA 40          // LDS row stride in shorts (80B rows)

typedef __attribute__((ext_vector_type(8))) short bf16x8;
typedef __attribute__((ext_vector_type(4))) float f32x4;

__device__ __forceinline__ float sspf(float x) {
    return fmaxf(x, 0.0f) + log1pf(expf(-fabsf(x))) - LOG2C;
}
__device__ __forceinline__ short f2bf(float x) {
    unsigned u = __float_as_uint(x);
    unsigned r = (u + 0x7FFF + ((u >> 16) & 1)) >> 16;   // RNE
    return (short)r;
}
__device__ __forceinline__ float bf2f(short h) {
    return __uint_as_float(((unsigned)(unsigned short)h) << 16);
}
__device__ __forceinline__ int packsplit(float x) {
    short hi = f2bf(x);
    short lo = f2bf(x - bf2f(hi));
    return ((int)hi << 16) | ((int)lo & 0xffff);
}
__device__ __forceinline__ float unpackf(int p) {
    float fh = __uint_as_float((unsigned)p & 0xffff0000u);
    float fl = __uint_as_float(((unsigned)p) << 16);
    return fh + fl;
}

// ---------------------------------------------------------------- MFMA GEMM
// outP = packsplit(op(A @ B + bias [+ unpack(outP)])). A: packed int [Ma][lda]
// (zero-padded cols). B: TRANSPOSED pre-split bf16 hi/lo [Nc][ldb] (zero-
// padded k). K % 32 == 0. Output ld = HP, pad cols 0. 1D grid, XCD swizzle.
// Staging rows clamped (no per-chunk guards); OOB contributions are masked
// by the epilogue (rows >= Ma skipped, cols >= Nc written 0).
template<bool BIAS, bool ACT, bool ACCUM>
__global__ __launch_bounds__(256, 6)
void gemm_mfma(const int* __restrict__ A, int lda,
               const short* __restrict__ Bh, const short* __restrict__ Bl, int ldb,
               const float* __restrict__ bias,
               int* __restrict__ outP,
               int Ma, int K, int Nc)
{
    const int NT = (Nc + TN - 1) / TN;
    const int f = blockIdx.x;
    const int xcd = f & 7, s = f >> 3;
    const int n0 = (s % NT) * TN;
    const int m0 = (xcd + 8 * (s / NT)) * TM;
    if (m0 >= Ma) return;

    __shared__ __align__(16) short As[2][TM * SA];
    __shared__ __align__(16) short Bs[2][TN * SA];

    const int tid = threadIdx.x;
    const int lane = tid & 63, wid = tid >> 6;
    const int wm = (wid >> 1) * 32, wn = (wid & 1) * 32;
    const int l15 = lane & 15, quad = lane >> 4;
    const int srow = tid >> 2;          // 0..63
    const int skk  = (tid & 3) << 3;    // 0,8,16,24

    // clamped staging pointers; advanced by TK per chunk
    const int gm = min(m0 + srow, Ma - 1);
    const int gn = min(n0 + srow, Nc - 1);
    const int*   aPtr  = A  + (size_t)gm * lda + skk;
    const short* bPtrH = Bh + (size_t)gn * ldb + skk;
    const short* bPtrL = Bl + (size_t)gn * ldb + skk;

    f32x4 acc[2][2];
    #pragma unroll
    for (int i = 0; i < 2; ++i)
        #pragma unroll
        for (int j = 0; j < 2; ++j)
            acc[i][j] = (f32x4){0.f, 0.f, 0.f, 0.f};

    int4 ra0, ra1;
    short4 rbh0, rbh1, rbl0, rbl1;

    // prefetch chunk 0
    ra0 = *(const int4*)aPtr; ra1 = *(const int4*)(aPtr + 4);
    rbh0 = *(const short4*)bPtrH; rbh1 = *(const short4*)(bPtrH + 4);
    rbl0 = *(const short4*)bPtrL; rbl1 = *(const short4*)(bPtrL + 4);
    aPtr += TK; bPtrH += TK; bPtrL += TK;

    for (int k0 = 0; k0 < K; k0 += TK) {
        {
            short4 vh0 = { (short)(ra0.x >> 16), (short)(ra0.y >> 16),
                           (short)(ra0.z >> 16), (short)(ra0.w >> 16) };
            short4 vl0 = { (short)ra0.x, (short)ra0.y, (short)ra0.z, (short)ra0.w };
            short4 vh1 = { (short)(ra1.x >> 16), (short)(ra1.y >> 16),
                           (short)(ra1.z >> 16), (short)(ra1.w >> 16) };
            short4 vl1 = { (short)ra1.x, (short)ra1.y, (short)ra1.z, (short)ra1.w };
            *(short4*)&As[0][srow * SA + skk]     = vh0;
            *(short4*)&As[0][srow * SA + skk + 4] = vh1;
            *(short4*)&As[1][srow * SA + skk]     = vl0;
            *(short4*)&As[1][srow * SA + skk + 4] = vl1;
            *(short4*)&Bs[0][srow * SA + skk]     = rbh0;
            *(short4*)&Bs[0][srow * SA + skk + 4] = rbh1;
            *(short4*)&Bs[1][srow * SA + skk]     = rbl0;
            *(short4*)&Bs[1][srow * SA + skk + 4] = rbl1;
        }
        __syncthreads();

        if (k0 + TK < K) {
            ra0 = *(const int4*)aPtr; ra1 = *(const int4*)(aPtr + 4);
            rbh0 = *(const short4*)bPtrH; rbh1 = *(const short4*)(bPtrH + 4);
            rbl0 = *(const short4*)bPtrL; rbl1 = *(const short4*)(bPtrL + 4);
            aPtr += TK; bPtrH += TK; bPtrL += TK;
        }

        bf16x8 a_h[2], a_l[2], b_h[2], b_l[2];
        #pragma unroll
        for (int mi = 0; mi < 2; ++mi) {
            int row = wm + mi * 16 + l15;
            a_h[mi] = *(const bf16x8*)&As[0][row * SA + quad * 8];
            a_l[mi] = *(const bf16x8*)&As[1][row * SA + quad * 8];
        }
        #pragma unroll
        for (int ni = 0; ni < 2; ++ni) {
            int col = wn + ni * 16 + l15;
            b_h[ni] = *(const bf16x8*)&Bs[0][col * SA + quad * 8];
            b_l[ni] = *(const bf16x8*)&Bs[1][col * SA + quad * 8];
        }

        #pragma unroll
        for (int mi = 0; mi < 2; ++mi)
            #pragma unroll
            for (int ni = 0; ni < 2; ++ni) {
                acc[mi][ni] = __builtin_amdgcn_mfma_f32_16x16x32_bf16(
                    a_h[mi], b_h[ni], acc[mi][ni], 0, 0, 0);
                acc[mi][ni] = __builtin_amdgcn_mfma_f32_16x16x32_bf16(
                    a_h[mi], b_l[ni], acc[mi][ni], 0, 0, 0);
                acc[mi][ni] = __builtin_amdgcn_mfma_f32_16x16x32_bf16(
                    a_l[mi], b_h[ni], acc[mi][ni], 0, 0, 0);
            }
        __syncthreads();
    }

    #pragma unroll
    for (int mi = 0; mi < 2; ++mi) {
        #pragma unroll
        for (int r = 0; r < 4; ++r) {
            int row = m0 + wm + mi * 16 + quad * 4 + r;
            if (row >= Ma) continue;
            #pragma unroll
            for (int ni = 0; ni < 2; ++ni) {
                int col = n0 + wn + ni * 16 + l15;
                if (col >= HP) continue;
                size_t idx = (size_t)row * HP + col;
                float v = 0.0f;
                if (col < Nc) {
                    v = acc[mi][ni][r];
                    if constexpr (BIAS) v += bias[col];
                    if constexpr (ACT)  v = sspf(v);
                    if constexpr (ACCUM) v += unpackf(outP[idx]);
                }
                outP[idx] = packsplit(v);
            }
        }
    }
}

// Batched slab GEMM over all L layers stacked in M (1024 rows per layer).
// SHAREDA: A rows are (m % 1024). Same clamping + pointer-increment scheme.
template<bool SHAREDA, bool ACT>
__global__ __launch_bounds__(256, 6)
void gemm_tab(const int* __restrict__ A, int lda,
              const short* __restrict__ BhBase, const short* __restrict__ BlBase,
              int ldb, int bstride,
              const float* __restrict__ biasBase,
              int* __restrict__ outP,
              int Ma, int K, int Nc)
{
    const int NT = (Nc + TN - 1) / TN;
    const int f = blockIdx.x;
    const int xcd = f & 7, s = f >> 3;
    const int n0 = (s % NT) * TN;
    const int m0 = (xcd + 8 * (s / NT)) * TM;
    if (m0 >= Ma) return;

    const int layer = m0 >> 10;                       // 1024 rows per layer
    const int arow0 = SHAREDA ? (m0 & 1023) : m0;
    const short* __restrict__ Bh = BhBase + (size_t)layer * bstride;
    const short* __restrict__ Bl = BlBase + (size_t)layer * bstride;
    const float* __restrict__ bias = biasBase + (size_t)layer * H_DIM;

    __shared__ __align__(16) short As[2][TM * SA];
    __shared__ __align__(16) short Bs[2][TN * SA];

    const int tid = threadIdx.x;
    const int lane = tid & 63, wid = tid >> 6;
    const int wm = (wid >> 1) * 32, wn = (wid & 1) * 32;
    const int l15 = lane & 15, quad = lane >> 4;
    const int srow = tid >> 2;
    const int skk  = (tid & 3) << 3;

    const int gn = min(n0 + srow, Nc - 1);
    const int*   aPtr  = A  + (size_t)(arow0 + srow) * lda + skk;
    const short* bPtrH = Bh + (size_t)gn * ldb + skk;
    const short* bPtrL = Bl + (size_t)gn * ldb + skk;

    f32x4 acc[2][2];
    #pragma unroll
    for (int i = 0; i < 2; ++i)
        #pragma unroll
        for (int j = 0; j < 2; ++j)
            acc[i][j] = (f32x4){0.f, 0.f, 0.f, 0.f};

    int4 ra0, ra1;
    short4 rbh0, rbh1, rbl0, rbl1;

    ra0 = *(const int4*)aPtr; ra1 = *(const int4*)(aPtr + 4);
    rbh0 = *(const short4*)bPtrH; rbh1 = *(const short4*)(bPtrH + 4);
    rbl0 = *(const short4*)bPtrL; rbl1 = *(const short4*)(bPtrL + 4);
    aPtr += TK; bPtrH += TK; bPtrL += TK;

    for (int k0 = 0; k0 < K; k0 += TK) {
        {
            short4 vh0 = { (short)(ra0.x >> 16), (short)(ra0.y >> 16),
                           (short)(ra0.z >> 16), (short)(ra0.w >> 16) };
            short4 vl0 = { (short)ra0.x, (short)ra0.y, (short)ra0.z, (short)ra0.w };
            short4 vh1 = { (short)(ra1.x >> 16), (short)(ra1.y >> 16),
                           (short)(ra1.z >> 16), (short)(ra1.w >> 16) };
            short4 vl1 = { (short)ra1.x, (short)ra1.y, (short)ra1.z, (short)ra1.w };
            *(short4*)&As[0][srow * SA + skk]     = vh0;
            *(short4*)&As[0][srow * SA + skk + 4] = vh1;
            *(short4*)&As[1][srow * SA + skk]     = vl0;
            *(short4*)&As[1][srow * SA + skk + 4] = vl1;
            *(short4*)&Bs[0][srow * SA + skk]     = rbh0;
            *(short4*)&Bs[0][srow * SA + skk + 4] = rbh1;
            *(short4*)&Bs[1][srow * SA + skk]     = rbl0;
            *(short4*)&Bs[1][srow * SA + skk + 4] = rbl1;
        }
        __syncthreads();

        if (k0 + TK < K) {
            ra0 = *(const int4*)aPtr; ra1 = *(const int4*)(aPtr + 4);
            rbh0 = *(const short4*)bPtrH; rbh1 = *(const short4*)(bPtrH + 4);
            rbl0 = *(const short4*)bPtrL; rbl1 = *(const short4*)(bPtrL + 4);
            aPtr += TK; bPtrH += TK; bPtrL += TK;
        }

        bf16x8 a_h[2], a_l[2], b_h[2], b_l[2];
        #pragma unroll
        for (int mi = 0; mi < 2; ++mi) {
            int row = wm + mi * 16 + l15;
            a_h[mi] = *(const bf16x8*)&As[0][row * SA + quad * 8];
            a_l[mi] = *(const bf16x8*)&As[1][row * SA + quad * 8];
        }
        #pragma unroll
        for (int ni = 0; ni < 2; ++ni) {
            int col = wn + ni * 16 + l15;
            b_h[ni] = *(const bf16x8*)&Bs[0][col * SA + quad * 8];
            b_l[ni] = *(const bf16x8*)&Bs[1][col * SA + quad * 8];
        }
        #pragma unroll
        for (int mi = 0; mi < 2; ++mi)
            #pragma unroll
            for (int ni = 0; ni < 2; ++ni) {
                acc[mi][ni] = __builtin_amdgcn_mfma_f32_16x16x32_bf16(
                    a_h[mi], b_h[ni], acc[mi][ni], 0, 0, 0);
                acc[mi][ni] = __builtin_amdgcn_mfma_f32_16x16x32_bf16(
                    a_h[mi], b_l[ni], acc[mi][ni], 0, 0, 0);
                acc[mi][ni] = __builtin_amdgcn_mfma_f32_16x16x32_bf16(
                    a_l[mi], b_h[ni], acc[mi][ni], 0, 0, 0);
            }
        __syncthreads();
    }

    #pragma unroll
    for (int mi = 0; mi < 2; ++mi) {
        #pragma unroll
        for (int r = 0; r < 4; ++r) {
            int row = m0 + wm + mi * 16 + quad * 4 + r;
            if (row >= Ma) continue;
            #pragma unroll
            for (int ni = 0; ni < 2; ++ni) {
                int col = n0 + wn + ni * 16 + l15;
                if (col >= HP) continue;
                float v = 0.0f;
                if (col < Nc) {
                    v = acc[mi][ni][r] + bias[col];
                    if constexpr (ACT) v = sspf(v);
                }
                outP[(size_t)row * HP + col] = packsplit(v);
            }
        }
    }
}

static inline dim3 mfma_grid(int Ma, int Nc) {
    int MB = (Ma + TM - 1) / TM;
    int NT = (Nc + TN - 1) / TN;
    int Ys = ((MB + 7) / 8) * 8;
    return dim3(Ys * NT);
}

// ---------------------------------------------------------------- fp32 GEMM (final pool matmul only)
#define BM 64
#define BN 64
#define BK 16
template<bool BIAS>
__global__ __launch_bounds__(256)
void gemm_k(const float* __restrict__ A, int lda,
            const float* __restrict__ W,
            const float* __restrict__ bias,
            float* __restrict__ out,
            int Ma, int K, int Nc)
{
    __shared__ __align__(16) float Asd[BK][BM];
    __shared__ __align__(16) float Bsd[BK][BN];
    const int tid = threadIdx.x;
    const int tx = tid & 15, ty = tid >> 4;
    const int m0 = blockIdx.y * BM, n0 = blockIdx.x * BN;
    const int ar = tid >> 2, ac = (tid & 3) << 2;
    const int br = tid >> 4, bc = (tid & 15) << 2;
    float acc[4][4] = {};
    for (int k0 = 0; k0 < K; k0 += BK) {
        {
            int row = m0 + ar, col = k0 + ac;
            float4 v = make_float4(0.f, 0.f, 0.f, 0.f);
            if (row < Ma) {
                const float* ap = A + (size_t)row * lda + col;
                if (col + 3 < K) v = *(const float4*)ap;
                else {
                    if (col + 0 < K) v.x = ap[0];
                    if (col + 1 < K) v.y = ap[1];
                    if (col + 2 < K) v.z = ap[2];
                }
            }
            Asd[ac + 0][ar] = v.x; Asd[ac + 1][ar] = v.y;
            Asd[ac + 2][ar] = v.z; Asd[ac + 3][ar] = v.w;
        }
        {
            int row = k0 + br, col = n0 + bc;
            float4 v = make_float4(0.f, 0.f, 0.f, 0.f);
            if (row < K && col + 3 < Nc)
                v = *(const float4*)(W + (size_t)row * Nc + col);
            *(float4*)&Bsd[br][bc] = v;
        }
        __syncthreads();
        #pragma unroll
        for (int kk = 0; kk < BK; ++kk) {
            float4 a4 = *(const float4*)&Asd[kk][ty << 2];
            float4 b4 = *(const float4*)&Bsd[kk][tx << 2];
            float av[4] = {a4.x, a4.y, a4.z, a4.w};
            float bv[4] = {b4.x, b4.y, b4.z, b4.w};
            #pragma unroll
            for (int i = 0; i < 4; ++i)
                #pragma unroll
                for (int j = 0; j < 4; ++j)
                    acc[i][j] = fmaf(av[i], bv[j], acc[i][j]);
        }
        __syncthreads();
    }
    #pragma unroll
    for (int i = 0; i < 4; ++i) {
        int row = m0 + (ty << 2) + i;
        if (row >= Ma) continue;
        #pragma unroll
        for (int j = 0; j < 4; ++j) {
            int col = n0 + (tx << 2) + j;
            if (col >= Nc) continue;
            float v = acc[i][j];
            if constexpr (BIAS) v += bias[col];
            out[(size_t)row * Nc + col] = v;
        }
    }
}

// ---------------------------------------------------------------- weight prep
__global__ __launch_bounds__(256)
void wts_w1_k(const float* __restrict__ w_all, short* __restrict__ oh,
              short* __restrict__ ol)
{
    __shared__ short th[64][65], tl[64][65];
    const int layer = blockIdx.z;
    const float* w = w_all + (size_t)layer * G_DIM * H_DIM;
    short* ohz = oh + (size_t)layer * H_DIM * 64;
    short* olz = ol + (size_t)layer * H_DIM * 64;
    const int n0 = blockIdx.y * 64;
    const int tid = threadIdx.x;
    #pragma unroll
    for (int p = 0; p < 4; ++p) {
        int k = p * 16 + (tid >> 4);
        int n4 = (tid & 15) << 2;
        float4 v = make_float4(0.f, 0.f, 0.f, 0.f);
        if (k < G_DIM && n0 + n4 + 3 < H_DIM)
            v = *(const float4*)(w + (size_t)k * H_DIM + n0 + n4);
        int px = packsplit(v.x), py = packsplit(v.y);
        int pz = packsplit(v.z), pw = packsplit(v.w);
        th[n4 + 0][k] = (short)(px >> 16); tl[n4 + 0][k] = (short)px;
        th[n4 + 1][k] = (short)(py >> 16); tl[n4 + 1][k] = (short)py;
        th[n4 + 2][k] = (short)(pz >> 16); tl[n4 + 2][k] = (short)pz;
        th[n4 + 3][k] = (short)(pw >> 16); tl[n4 + 3][k] = (short)pw;
    }
    __syncthreads();
    #pragma unroll
    for (int p = 0; p < 4; ++p) {
        int n = p * 16 + (tid >> 4);
        int k4 = (tid & 15) << 2;
        if (n0 + n >= H_DIM) continue;
        short4 sh = { th[n][k4], th[n][k4 + 1], th[n][k4 + 2], th[n][k4 + 3] };
        short4 sl = { tl[n][k4], tl[n][k4 + 1], tl[n][k4 + 2], tl[n][k4 + 3] };
        *(short4*)(ohz + (size_t)(n0 + n) * 64 + k4) = sh;
        *(short4*)(olz + (size_t)(n0 + n) * 64 + k4) = sl;
    }
}

__global__ __launch_bounds__(256)
void wts_big_k(const float* __restrict__ w2, const float* __restrict__ l1,
               const float* __restrict__ l2, const float* __restrict__ iw,
               short* __restrict__ oh2, short* __restrict__ ol2,
               short* __restrict__ oh1, short* __restrict__ ol1,
               short* __restrict__ ohl2, short* __restrict__ oll2,
               short* __restrict__ ohi, short* __restrict__ oli)
{
    __shared__ short th[64][65], tl[64][65];
    const int z = blockIdx.z, type = z / L_LAYERS, layer = z % L_LAYERS;
    const float* w; short* oh; short* ol;
    if (type == 0)      { w = w2; oh = oh2; ol = ol2; }
    else if (type == 1) { w = l1; oh = oh1; ol = ol1; }
    else if (type == 2) { w = l2; oh = ohl2; ol = oll2; }
    else                { w = iw; oh = ohi; ol = oli; }
    w  += (size_t)layer * H_DIM * H_DIM;
    oh += (size_t)layer * H_DIM * HP;
    ol += (size_t)layer * H_DIM * HP;
    const int k0 = blockIdx.x * 64, n0 = blockIdx.y * 64;
    const int tid = threadIdx.x;
    #pragma unroll
    for (int p = 0; p < 4; ++p) {
        int k = p * 16 + (tid >> 4);
        int n4 = (tid & 15) << 2;
        float4 v = make_float4(0.f, 0.f, 0.f, 0.f);
        if (k0 + k < H_DIM && n0 + n4 + 3 < H_DIM)
            v = *(const float4*)(w + (size_t)(k0 + k) * H_DIM + n0 + n4);
        int px = packsplit(v.x), py = packsplit(v.y);
        int pz = packsplit(v.z), pw = packsplit(v.w);
        th[n4 + 0][k] = (short)(px >> 16); tl[n4 + 0][k] = (short)px;
        th[n4 + 1][k] = (short)(py >> 16); tl[n4 + 1][k] = (short)py;
        th[n4 + 2][k] = (short)(pz >> 16); tl[n4 + 2][k] = (short)pz;
        th[n4 + 3][k] = (short)(pw >> 16); tl[n4 + 3][k] = (short)pw;
    }
    __syncthreads();
    #pragma unroll
    for (int p = 0; p < 4; ++p) {
        int n = p * 16 + (tid >> 4);
        int k4 = (tid & 15) << 2;
        if (n0 + n >= H_DIM || k0 + k4 > HP - 4) continue;
        short4 sh = { th[n][k4], th[n][k4 + 1], th[n][k4 + 2], th[n][k4 + 3] };
        short4 sl = { tl[n][k4], tl[n][k4 + 1], tl[n][k4 + 2], tl[n][k4 + 3] };
        *(short4*)(oh + (size_t)(n0 + n) * HP + k0 + k4) = sh;
        *(short4*)(ol + (size_t)(n0 + n) * HP + k0 + k4) = sl;
    }
}

// ---------------------------------------------------------------- helpers
__global__ __launch_bounds__(256)
void init_h_k(const int* __restrict__ z, const float* __restrict__ emb,
              int* __restrict__ hP)
{
    int t = blockIdx.x * 256 + threadIdx.x;
    const int QC = HP / 4;   // 152
    if (t >= N_ATOMS * QC) return;
    int i = t / QC;
    int q = (t - i * QC) << 2;
    size_t idx = (size_t)i * HP + q;
    if (q < H_DIM) {
        float4 v = *(const float4*)(emb + (size_t)z[i] * H_DIM + q);
        *(int4*)(hP + idx) = make_int4(packsplit(v.x), packsplit(v.y),
                                       packsplit(v.z), packsplit(v.w));
    } else {
        *(int4*)(hP + idx) = make_int4(0, 0, 0, 0);
    }
}

// per-edge record: {src*HP, i0*HP, a = C - f*C, b = f*C}
__global__ __launch_bounds__(256)
void edge_geom_k(const float* __restrict__ pos, const int* __restrict__ src,
                 const int* __restrict__ dst, float4* __restrict__ einfo)
{
    int e = blockIdx.x * 256 + threadIdx.x;
    if (e >= E_EDGES) return;
    int s = src[e], d0 = dst[e];
    float dx = pos[s * 3 + 0] - pos[d0 * 3 + 0];
    float dy = pos[s * 3 + 1] - pos[d0 * 3 + 1];
    float dz = pos[s * 3 + 2] - pos[d0 * 3 + 2];
    float dist = sqrtf(dx * dx + dy * dy + dz * dz + 1e-12f);
    float cc = 0.5f * (cosf(dist * 0.31415926535f) + 1.0f);
    float u = dist * ((float)(M_TAB - 1) / DMAX);
    u = fminf(fmaxf(u, 0.0f), (float)(M_TAB - 1) - 0.001f);
    int i0 = (int)u;
    float fc = (u - (float)i0) * cc;
    einfo[e] = make_float4(__int_as_float(s * HP),
                           __int_as_float(i0 * HP),
                           cc - fc, fc);
}

__global__ __launch_bounds__(256)
void rbf_tab_k(int* __restrict__ rtabP)
{
    int t = blockIdx.x * 256 + threadIdx.x;
    if (t >= M_TAB * 64) return;
    int i = t >> 6, g = t & 63;
    float v = 0.0f;
    if (g < G_DIM) {
        float dg  = (float)i * (DMAX / (float)(M_TAB - 1));
        float off = (float)g * (10.0f / 49.0f);
        float x = dg - off;
        const float coeff = -0.5f * (49.0f / 10.0f) * (49.0f / 10.0f);
        v = expf(coeff * x * x);
    }
    rtabP[t] = packsplit(v);
}

// ---------------------------------------------------------------- CSR build
__global__ __launch_bounds__(256)
void hist_k(const int* __restrict__ dst, int* __restrict__ deg)
{
    int e = blockIdx.x * 256 + threadIdx.x;
    if (e >= E_EDGES) return;
    atomicAdd(&deg[dst[e]], 1);
}

__global__ __launch_bounds__(1024)
void scan_k(const int* __restrict__ deg, int* __restrict__ rowptr)
{
    __shared__ int sums[1024];
    int tid = threadIdx.x;
    const int CHUNK = (N_ATOMS + 1023) / 1024;
    int base = tid * CHUNK;
    int local[16];
    int s = 0;
    #pragma unroll
    for (int c = 0; c < 16; ++c) {
        if (c >= CHUNK) break;
        int idx = base + c;
        local[c] = s;
        s += (idx < N_ATOMS) ? deg[idx] : 0;
    }
    sums[tid] = s;
    __syncthreads();
    for (int off = 1; off < 1024; off <<= 1) {
        int v = (tid >= off) ? sums[tid - off] : 0;
        __syncthreads();
        sums[tid] += v;
        __syncthreads();
    }
    int prefix = (tid > 0) ? sums[tid - 1] : 0;
    #pragma unroll
    for (int c = 0; c < 16; ++c) {
        if (c >= CHUNK) break;
        int idx = base + c;
        if (idx <= N_ATOMS) rowptr[idx] = prefix + local[c];
    }
    if (tid == 1023) rowptr[N_ATOMS] = sums[1023];
}

__global__ __launch_bounds__(256)
void fill_k(const int* __restrict__ dst, const float4* __restrict__ einfo,
            const int* __restrict__ rowptr, int* __restrict__ cursor,
            float4* __restrict__ esorted)
{
    int e = blockIdx.x * 256 + threadIdx.x;
    if (e >= E_EDGES) return;
    int d0 = dst[e];
    int pos = rowptr[d0] + atomicAdd(&cursor[d0], 1);
    esorted[pos] = einfo[e];
}

// molecule boundaries via binary search over the SORTED batch array
__global__ __launch_bounds__(256)
void bounds_k(const int* __restrict__ batch, int* __restrict__ mrow)
{
    int b = threadIdx.x;
    if (b > B_MOLS) return;
    int lo = 0, hi = N_ATOMS;
    while (lo < hi) {
        int mid = (lo + hi) >> 1;
        if (batch[mid] < b) lo = mid + 1; else hi = mid;
    }
    mrow[b] = lo;
}

// ---------------------------------------------------------------- gather
__device__ __forceinline__ void gacc(float4& acc, const int* yP, const int* wtP,
                                     const float4& ei, int q)
{
    int srow = __float_as_int(ei.x);
    int wrow = __float_as_int(ei.y);
    float a = ei.z, b = ei.w;
    int4 yv = *(const int4*)(yP + srow + q);
    int4 w0 = *(const int4*)(wtP + wrow + q);
    int4 w1 = *(const int4*)(wtP + wrow + HP + q);
    acc.x += unpackf(yv.x) * (a * unpackf(w0.x) + b * unpackf(w1.x));
    acc.y += unpackf(yv.y) * (a * unpackf(w0.y) + b * unpackf(w1.y));
    acc.z += unpackf(yv.z) * (a * unpackf(w0.z) + b * unpackf(w1.z));
    acc.w += unpackf(yv.w) * (a * unpackf(w0.w) + b * unpackf(w1.w));
}

__global__ __launch_bounds__(256)
void gather_k(const int* __restrict__ yP, const int* __restrict__ wtP,
              const int* __restrict__ rowptr, const float4* __restrict__ esorted,
              int* __restrict__ aggP)
{
    int t = blockIdx.x * 256 + threadIdx.x;
    const int QC = HP / 4;   // 152
    if (t >= N_ATOMS * QC) return;
    int i = t / QC;
    int q = (t - i * QC) << 2;
    size_t idx = (size_t)i * HP + q;
    if (q >= H_DIM) { *(int4*)(aggP + idx) = make_int4(0, 0, 0, 0); return; }
    int j0 = rowptr[i], j1 = rowptr[i + 1];
    float4 a0 = make_float4(0.f, 0.f, 0.f, 0.f);
    float4 a1 = make_float4(0.f, 0.f, 0.f, 0.f);
    int j = j0;
    for (; j + 2 <= j1; j += 2) {
        float4 e0 = esorted[j], e1 = esorted[j + 1];
        gacc(a0, yP, wtP, e0, q);
        gacc(a1, yP, wtP, e1, q);
    }
    if (j < j1) gacc(a0, yP, wtP, esorted[j], q);
    a0.x += a1.x; a0.y += a1.y; a0.z += a1.z; a0.w += a1.w;
    *(int4*)(aggP + idx) = make_int4(packsplit(a0.x), packsplit(a0.y),
                                     packsplit(a0.z), packsplit(a0.w));
}

// ---------------------------------------------------------------- pool (segment mean, no atomics)
__global__ __launch_bounds__(256)
void pool_seg_k(const int* __restrict__ hP, const int* __restrict__ mrow,
                float* __restrict__ pooled)
{
    int b = blockIdx.x;
    int t = threadIdx.x;
    if (t >= 150) return;               // cols 600..607 are pad
    int q = t << 2;
    int a = mrow[b], a1 = mrow[b + 1];
    float cnt = (float)(a1 - a);
    float4 s0 = make_float4(0.f, 0.f, 0.f, 0.f);
    float4 s1 = make_float4(0.f, 0.f, 0.f, 0.f);
    for (; a + 2 <= a1; a += 2) {
        int4 p0 = *(const int4*)(hP + (size_t)a * HP + q);
        int4 p1 = *(const int4*)(hP + (size_t)(a + 1) * HP + q);
        s0.x += unpackf(p0.x); s0.y += unpackf(p0.y);
        s0.z += unpackf(p0.z); s0.w += unpackf(p0.w);
        s1.x += unpackf(p1.x); s1.y += unpackf(p1.y);
        s1.z += unpackf(p1.z); s1.w += unpackf(p1.w);
    }
    if (a < a1) {
        int4 p0 = *(const int4*)(hP + (size_t)a * HP + q);
        s0.x += unpackf(p0.x); s0.y += unpackf(p0.y);
        s0.z += unpackf(p0.z); s0.w += unpackf(p0.w);
    }
    float inv = 1.0f / fmaxf(cnt, 1.0f);
    float4 o = make_float4((s0.x + s1.x) * inv, (s0.y + s1.y) * inv,
                           (s0.z + s1.z) * inv, (s0.w + s1.w) * inv);
    *(float4*)(pooled + (size_t)b * H_DIM + q) = o;
}

// ---------------------------------------------------------------- launch
extern "C" void kernel_launch(void* const* d_in, const int* in_sizes, int n_in,
                              void* d_out, int out_size, void* d_ws, size_t ws_size,
                              hipStream_t stream)
{
    const int*   z      = (const int*)  d_in[0];
    const float* pos    = (const float*)d_in[1];
    const int*   batch  = (const int*)  d_in[2];
    const int*   eidx   = (const int*)  d_in[3];
    const float* emb    = (const float*)d_in[4];
    const float* mlp_w1 = (const float*)d_in[5];
    const float* mlp_b1 = (const float*)d_in[6];
    const float* mlp_w2 = (const float*)d_in[7];
    const float* mlp_b2 = (const float*)d_in[8];
    const float* lin1_w = (const float*)d_in[9];
    const float* lin2_w = (const float*)d_in[10];
    const float* lin2_b = (const float*)d_in[11];
    const float* intw   = (const float*)d_in[12];
    const float* intb   = (const float*)d_in[13];
    const float* poolw  = (const float*)d_in[14];
    const float* poolb  = (const float*)d_in[15];

    float* ws = (float*)d_ws;
    const size_t NHP = (size_t)N_ATOMS * HP;       // 6,080,000
    const size_t TABALL = (size_t)L_LAYERS * M_TAB * HP;   // 3,735,552

    int*   hP    = (int*)ws;                       // NHP
    int*   y1P   = (int*)(ws + NHP);               // NHP; aliases tP, ttabA
    int*   tP    = y1P;
    int*   ttabA = y1P;                            // prep-time alias (3.7M <= NHP)
    int*   aggP  = (int*)(ws + 2 * NHP);           // NHP
    // aggP region aliases — ONLY prep-phase data that's dead before gather:
    float4* einfo  = (float4*)aggP;                          // 256,000 f
    int*    deg    = (int*)((float*)aggP + 300000);          // 10,000
    int*    cursor = (int*)((float*)aggP + 310000);          // 10,000
    int*   wtabA = (int*)(ws + 3 * NHP);           // TABALL (persistent)
    int*   rtabP = (int*)(ws + 3 * NHP + TABALL);  // M_TAB*64 = 65,536
    short* wtH   = (short*)(ws + 3 * NHP + TABALL + (size_t)M_TAB * 64);
    short* wtL   = wtH + 8985600;
    // persistent tail (NOT aliased): esorted, pooled, rowptr, mrow
    float*  tailF   = (float*)(wtL + 8985600);
    float4* esorted = (float4*)tailF;                        // 256,000 f
    float*  pooled  = tailF + 256000;                        // 76,800 f
    int*    rowptr  = (int*)(tailF + 332800);                // 10,001
    int*    mrow    = rowptr + 10001;                        // 129

    short* w1t_h = wtH;                       short* w1t_l = wtL;
    short* w2t_h = wtH + 230400;              short* w2t_l = wtL + 230400;
    short* l1t_h = w2t_h + 6 * 600 * HP;      short* l1t_l = w2t_l + 6 * 600 * HP;
    short* l2t_h = l1t_h + 6 * 600 * HP;      short* l2t_l = l1t_l + 6 * 600 * HP;
    short* int_h = l2t_h + 6 * 600 * HP;      short* int_l = l2t_l + 6 * 600 * HP;

    const int* src = eidx;
    const int* dst = eidx + E_EDGES;

    const dim3 blk(256);
    const int QC = HP / 4;
    const dim3 gN   = mfma_grid(N_ATOMS, H_DIM);            // 1600
    const dim3 gTab = mfma_grid(L_LAYERS * M_TAB, H_DIM);   // 960

    // ---- one-time prep (einfo/deg/cursor alias aggP: dead before gather)
    edge_geom_k<<<(E_EDGES + 255) / 256, blk, 0, stream>>>(pos, src, dst, einfo);
    hipMemsetAsync(deg, 0, 2 * N_ATOMS * sizeof(int), stream);
    hist_k <<<(E_EDGES + 255) / 256, blk, 0, stream>>>(dst, deg);
    scan_k <<<1, 1024, 0, stream>>>(deg, rowptr);
    fill_k <<<(E_EDGES + 255) / 256, blk, 0, stream>>>(dst, einfo, rowptr, cursor, esorted);
    bounds_k <<<1, 256, 0, stream>>>(batch, mrow);
    init_h_k <<<(N_ATOMS * QC + 255) / 256, blk, 0, stream>>>(z, emb, hP);
    rbf_tab_k<<<(M_TAB * 64 + 255) / 256,   blk, 0, stream>>>(rtabP);
    wts_w1_k  <<<dim3(1, 10, 6),   blk, 0, stream>>>(mlp_w1, w1t_h, w1t_l);
    wts_big_k <<<dim3(10, 10, 24), blk, 0, stream>>>(
        mlp_w2, lin1_w, lin2_w, intw,
        w2t_h, w2t_l, l1t_h, l1t_l, l2t_h, l2t_l, int_h, int_l);

    // ---- all 6 layers' filter tables in 2 batched slab GEMMs
    gemm_tab<true, true><<<gTab, blk, 0, stream>>>(
        rtabP, 64, w1t_h, w1t_l, 64, 600 * 64, mlp_b1,
        ttabA, L_LAYERS * M_TAB, 64, H_DIM);
    gemm_tab<false, false><<<gTab, blk, 0, stream>>>(
        ttabA, HP, w2t_h, w2t_l, HP, 600 * HP, mlp_b2,
        wtabA, L_LAYERS * M_TAB, HP, H_DIM);

    for (int k = 0; k < L_LAYERS; ++k) {
        const float* l2b = lin2_b + (size_t)k * H_DIM;
        const float* ib  = intb   + (size_t)k * H_DIM;
        const short* l1h = l1t_h + (size_t)k * H_DIM * HP;
        const short* l1l = l1t_l + (size_t)k * H_DIM * HP;
        const short* l2h = l2t_h + (size_t)k * H_DIM * HP;
        const short* l2l = l2t_l + (size_t)k * H_DIM * HP;
        const short* ih  = int_h + (size_t)k * H_DIM * HP;
        const short* il  = int_l + (size_t)k * H_DIM * HP;
        const int*   wtP = wtabA + (size_t)k * M_TAB * HP;

        // y1P = packsplit(h @ lin1)
        gemm_mfma<false, false, false><<<gN, blk, 0, stream>>>(
            hP, HP, l1h, l1l, HP, nullptr, y1P, N_ATOMS, HP, H_DIM);
        // aggP = packsplit(CSR-gather(y1 * W(d) * C))
        gather_k<<<(N_ATOMS * QC + 255) / 256, blk, 0, stream>>>(
            y1P, wtP, rowptr, esorted, aggP);
        // tP = packsplit(ssp(agg @ lin2 + b))   (aliases y1P)
        gemm_mfma<true, true, false><<<gN, blk, 0, stream>>>(
            aggP, HP, l2h, l2l, HP, l2b, tP, N_ATOMS, HP, H_DIM);
        // hP = packsplit(unpack(hP) + t @ int_w + ib)
        gemm_mfma<true, false, true><<<gN, blk, 0, stream>>>(
            tP, HP, ih, il, HP, ib, hP, N_ATOMS, HP, H_DIM);
    }

    // segment-mean pool (sorted batch, no atomics), then out = pooled @ pool_w + b
    pool_seg_k<<<B_MOLS, blk, 0, stream>>>(hP, mrow, pooled);
    gemm_k<true><<<dim3((H_DIM + BN - 1) / BN, (B_MOLS + BM - 1) / BM), blk, 0, stream>>>(
        pooled, H_DIM, poolw, poolb, (float*)d_out, B_MOLS, H_DIM, H_DIM);
}